// Round 2
// baseline (376.201 us; speedup 1.0000x reference)
//
#include <hip/hip_runtime.h>
#include <hip/hip_bf16.h>

// InstanceAttentionModule: B=32, H=W=32 (HW=1024), C=256, F=64, K_NEIGH=32.
// Round-2 structure (3 kernels):
//   k_prep : embW||attnW -> bf16 Wb[320][256] (once; was re-converted per block)
//   k_lin  : fused emb+shortcut GEMM (N=320) from one x staging.
//            outputs: embb bf16, sq fp32 (from ROUNDED emb), scT bf16 [b][c][j], Tinst
//   k_attn : fused scores+softmax+out per 32-row block (1024 blocks -> 4/CU):
//            phase A: gram via MFMA, E=exp(exp(-d2)-1+mask) -> global (L2-hot), R in LDS
//            phase B: u=exp(relu(E/R - T)) in regs, GEMM V=u@scT with Z=sum(u) fused,
//                     out = x + V/Z.  (k_z and both global E re-reads eliminated)

typedef short bf16x8 __attribute__((ext_vector_type(8)));
typedef float f32x4 __attribute__((ext_vector_type(4)));

__device__ __forceinline__ unsigned short f2bf(float f) {
  unsigned u = __float_as_uint(f);
  u += 0x7fffu + ((u >> 16) & 1u);   // round-to-nearest-even
  return (unsigned short)(u >> 16);
}
__device__ __forceinline__ float bf2f(unsigned short h) {
  return __uint_as_float(((unsigned)h) << 16);
}
__device__ __forceinline__ unsigned pack2(float a, float b) {
  return (unsigned)f2bf(a) | ((unsigned)f2bf(b) << 16);
}
__device__ __forceinline__ f32x4 mfma16(bf16x8 a, bf16x8 b, f32x4 c) {
  return __builtin_amdgcn_mfma_f32_16x16x32_bf16(a, b, c, 0, 0, 0);
}
__device__ __forceinline__ int iabs(int v) { return v < 0 ? -v : v; }

// ---------------------------------------------------------------- k_prep
// Convert embW (64x256) || attnW (256x256) -> bf16, row-concatenated.
__global__ __launch_bounds__(256) void k_prep(const float* __restrict__ embW,
                                              const float* __restrict__ attnW,
                                              unsigned short* __restrict__ Wb) {
  int i = blockIdx.x * 256 + threadIdx.x;   // grid 320 -> 81920 elements
  float v = (i < 16384) ? embW[i] : attnW[i - 16384];
  Wb[i] = f2bf(v);
}

// ---------------------------------------------------------------- k_lin
// grid 512 (64-row M-tiles), block 256 = 4 waves (wm x wn = 2x2).
// Wave tile: 32 rows x 160 cols of the concatenated N=320 output.
// x staged ONCE (K=256 fully in LDS); B-fragments direct from global bf16 Wb.
__global__ __launch_bounds__(256) void k_lin(const float* __restrict__ x,
                                             const unsigned short* __restrict__ Wb,
                                             const float* __restrict__ embB,
                                             const float* __restrict__ attnB,
                                             const float* __restrict__ thrW,
                                             const float* __restrict__ thrB,
                                             unsigned short* __restrict__ embb,
                                             float* __restrict__ sq,
                                             unsigned short* __restrict__ scT,
                                             float* __restrict__ Tout) {
  extern __shared__ char smem[];
  unsigned short (*xs)[264] = (unsigned short(*)[264])smem;  // 64x264x2 = 33792 B
  unsigned short (*St)[72]  = (unsigned short(*)[72])smem;   // 256x72x2 = 36864 B (reused)
  const int t = threadIdx.x;
  const int Mbase = blockIdx.x * 64;
  const int lane = t & 63, wave = t >> 6;
  const int wm = wave >> 1, wn = wave & 1;
  const int l15 = lane & 15, quad = lane >> 4;

  { // stage x tile 64x256 -> bf16, fully coalesced (1KB contiguous per i)
    const float* xt = x + (size_t)Mbase * 256;
    for (int i = 0; i < 16; i++) {
      float4 a = *(const float4*)(xt + i * 1024 + t * 4);
      int row = i * 4 + wave, col = lane * 4;
      uint2 p; p.x = pack2(a.x, a.y); p.y = pack2(a.z, a.w);
      *(uint2*)&xs[row][col] = p;
    }
  }
  __syncthreads();

  f32x4 acc[2][10] = {};
  for (int k0 = 0; k0 < 256; k0 += 32) {
    bf16x8 af[2];
    af[0] = *(const bf16x8*)&xs[wm * 32 + l15][k0 + quad * 8];
    af[1] = *(const bf16x8*)&xs[wm * 32 + 16 + l15][k0 + quad * 8];
    for (int nt = 0; nt < 10; nt++) {
      int n = wn * 160 + nt * 16 + l15;
      bf16x8 bfr = *(const bf16x8*)(Wb + (size_t)n * 256 + k0 + quad * 8);
      acc[0][nt] = mfma16(af[0], bfr, acc[0][nt]);
      acc[1][nt] = mfma16(af[1], bfr, acc[1][nt]);
    }
  }
  __syncthreads();   // xs dead; St takes over the same LDS

  // emb epilogue (wn==0 waves own n<64) + per-row sq of ROUNDED emb
  if (wn == 0) {
    float sp[2][4] = {{0.f,0.f,0.f,0.f},{0.f,0.f,0.f,0.f}};
    for (int rt = 0; rt < 2; rt++)
      for (int nt = 0; nt < 4; nt++) {
        int n = nt * 16 + l15;
        float bias = embB[n];
        for (int r = 0; r < 4; r++) {
          float v = acc[rt][nt][r] + bias;
          unsigned short hb = f2bf(v);
          int row = wm * 32 + rt * 16 + quad * 4 + r;
          embb[(size_t)(Mbase + row) * 64 + n] = hb;
          float vf = bf2f(hb);
          sp[rt][r] += vf * vf;
        }
      }
    for (int m = 8; m >= 1; m >>= 1)
      for (int rt = 0; rt < 2; rt++)
        for (int r = 0; r < 4; r++)
          sp[rt][r] += __shfl_xor(sp[rt][r], m);
    if (l15 == 0)
      for (int rt = 0; rt < 2; rt++)
        for (int r = 0; r < 4; r++)
          sq[Mbase + wm * 32 + rt * 16 + quad * 4 + r] = sp[rt][r];
  }

  // shortcut epilogue -> St transpose buffer
  for (int rt = 0; rt < 2; rt++)
    for (int nt = 0; nt < 10; nt++) {
      int n = wn * 160 + nt * 16 + l15;
      if (n < 64) continue;
      int c = n - 64;
      float bias = attnB[c];
      for (int r = 0; r < 4; r++) {
        float v = acc[rt][nt][r] + bias;
        St[c][wm * 32 + rt * 16 + quad * 4 + r] = f2bf(v);
      }
    }
  __syncthreads();

  const int b = Mbase >> 10, jbase = Mbase & 1023;
  { // coalesced write of shortcutT[b][c][jbase..jbase+64)
    unsigned short* dst = scT + ((size_t)b * 256 + t) * 1024 + jbase;
    for (int s = 0; s < 8; s++)
      *(uint4*)(dst + s * 8) = *(const uint4*)&St[t][s * 8];
  }
  { // Tinst
    float tp = 0.f;
    int j = t >> 2, cs = (t & 3) * 64;
    for (int c = 0; c < 64; c++)
      tp += bf2f(St[cs + c][j]) * thrW[cs + c];
    tp += __shfl_xor(tp, 1);
    tp += __shfl_xor(tp, 2);
    if ((t & 3) == 0) Tout[Mbase + j] = tp + thrB[0];
  }
}

// ---------------------------------------------------------------- k_attn
// grid 1024 (32 b x 32 row-blocks of 32 rows), block 256 = 4 waves.
// Phase A: waves split (rows 16 x j-half 512); gram MFMA -> E (global, L2-hot) + R (LDS).
// Phase B: waves 2x2 over 32 rows x 256 cols; A-frags = u built in registers from E;
//          Z accumulated fp32 alongside; epilogue out = x + V/Z.
__global__ __launch_bounds__(256) void k_attn(const unsigned short* __restrict__ embb,
                                              const float* __restrict__ sq,
                                              const float* __restrict__ T,
                                              const unsigned short* __restrict__ scT,
                                              const float* __restrict__ x,
                                              unsigned short* __restrict__ E,
                                              float* __restrict__ out) {
  __shared__ unsigned short Bs[256][40];   // scT K-tile, padded (free 2-way)
  __shared__ float rbuf[32];
  __shared__ float zbuf[32];
  const int t = threadIdx.x, lane = t & 63, wave = t >> 6;
  const int l15 = lane & 15, quad = lane >> 4;
  const int b = blockIdx.x >> 5, rb = (blockIdx.x & 31) * 32;

  if (t < 32) rbuf[t] = 0.f;
  __syncthreads();

  // ---------------- phase A: E + R
  {
    const unsigned short* eb = embb + (size_t)b * 1024 * 64;
    const int rhalf = (wave & 1) * 16, jhalf = (wave >> 1) * 512;
    const int rowA = rb + rhalf + l15;
    bf16x8 a0 = *(const bf16x8*)(eb + (size_t)rowA * 64 + quad * 8);
    bf16x8 a1 = *(const bf16x8*)(eb + (size_t)rowA * 64 + 32 + quad * 8);
    const int rowC = rb + rhalf + quad * 4;
    float sqi[4]; int yi[4], xi[4];
    for (int r = 0; r < 4; r++) {
      sqi[r] = sq[b * 1024 + rowC + r];
      yi[r] = (rowC + r) >> 5; xi[r] = (rowC + r) & 31;
    }
    float rp[4] = {0.f, 0.f, 0.f, 0.f};
    for (int j0 = jhalf; j0 < jhalf + 512; j0 += 16) {
      int jr = j0 + l15;
      bf16x8 b0 = *(const bf16x8*)(eb + (size_t)jr * 64 + quad * 8);
      bf16x8 b1 = *(const bf16x8*)(eb + (size_t)jr * 64 + 32 + quad * 8);
      f32x4 g = {0.f, 0.f, 0.f, 0.f};
      g = mfma16(a0, b0, g);
      g = mfma16(a1, b1, g);
      float sqj = sq[b * 1024 + jr];
      int yj = jr >> 5, xj = jr & 31;
      for (int r = 0; r < 4; r++) {
        float d2 = fmaxf(sqi[r] + sqj - 2.f * g[r], 0.f);
        int diff = iabs(yi[r] - yj) + iabs(xi[r] - xj);
        float m = (diff <= 32) ? (float)diff * (1.f / 32.f) : 0.f;
        float s = __expf(-d2) - 1.f + m;
        float e = __expf(s);
        E[((size_t)(b * 1024 + rowC + r)) * 1024 + jr] = f2bf(e);
        rp[r] += e;
      }
    }
    for (int m = 8; m >= 1; m >>= 1)
      for (int r = 0; r < 4; r++) rp[r] += __shfl_xor(rp[r], m);
    if (l15 == 0)
      for (int r = 0; r < 4; r++)
        atomicAdd(&rbuf[rhalf + quad * 4 + r], rp[r]);
  }
  __threadfence();   // E stores -> L2 visible before phase B reads
  __syncthreads();

  // ---------------- phase B: V = u @ scT, Z = sum(u), out = x + V/Z
  const int wm = wave >> 1, wn = wave & 1;
  const float invR = 1.f / rbuf[wm * 16 + l15];
  const unsigned short* Eb = E + ((size_t)(b * 1024 + rb + wm * 16 + l15)) * 1024;
  const float* Tb = T + b * 1024;
  const unsigned short* sb = scT + (size_t)b * 256 * 1024;

  f32x4 acc[8] = {};
  float z = 0.f;
  for (int j0 = 0; j0 < 1024; j0 += 32) {
    { // stage Bs[c][k] = scT[b][c][j0+k]
      const unsigned short* src = sb + (size_t)t * 1024 + j0;
      *(uint4*)&Bs[t][0]  = *(const uint4*)(src);
      *(uint4*)&Bs[t][8]  = *(const uint4*)(src + 8);
      *(uint4*)&Bs[t][16] = *(const uint4*)(src + 16);
      *(uint4*)&Bs[t][24] = *(const uint4*)(src + 24);
    }
    __syncthreads();
    union { float4 v[2]; float f[8]; } tv;
    tv.v[0] = *(const float4*)(Tb + j0 + quad * 8);
    tv.v[1] = *(const float4*)(Tb + j0 + quad * 8 + 4);
    union { uint4 v; unsigned short s[8]; } ev;
    ev.v = *(const uint4*)(Eb + j0 + quad * 8);
    union { bf16x8 v; unsigned short s[8]; } fr;
    for (int jj = 0; jj < 8; jj++) {
      float u = __expf(fmaxf(fmaf(bf2f(ev.s[jj]), invR, -tv.f[jj]), 0.f));
      z += u;
      fr.s[jj] = f2bf(u);
    }
    for (int nt = 0; nt < 8; nt++) {
      bf16x8 bfr = *(const bf16x8*)&Bs[wn * 128 + nt * 16 + l15][quad * 8];
      acc[nt] = mfma16(fr.v, bfr, acc[nt]);
    }
    __syncthreads();
  }
  z += __shfl_xor(z, 16);
  z += __shfl_xor(z, 32);
  if (wn == 0 && quad == 0) zbuf[wm * 16 + l15] = z;
  __syncthreads();

  for (int r = 0; r < 4; r++) {
    int il = wm * 16 + quad * 4 + r;
    float invZ = 1.f / zbuf[il];
    for (int nt = 0; nt < 8; nt++) {
      int c = wn * 128 + nt * 16 + l15;
      size_t idx = ((size_t)(b * 1024 + rb + il)) * 256 + c;
      out[idx] = x[idx] + acc[nt][r] * invZ;
    }
  }
}

// ---------------------------------------------------------------- launch
extern "C" void kernel_launch(void* const* d_in, const int* in_sizes, int n_in,
                              void* d_out, int out_size, void* d_ws, size_t ws_size,
                              hipStream_t stream) {
  const float* x     = (const float*)d_in[0];
  const float* embW  = (const float*)d_in[1];
  const float* embB  = (const float*)d_in[2];
  const float* attnW = (const float*)d_in[3];
  const float* attnB = (const float*)d_in[4];
  const float* thrW  = (const float*)d_in[5];
  const float* thrB  = (const float*)d_in[6];
  float* out = (float*)d_out;

  char* ws = (char*)d_ws;
  // layout: embb 4MB | scT 16MB | E 64MB | Wb 160K | sq 128K | T 128K  (<= 84.5MB as before)
  unsigned short* embb = (unsigned short*)(ws);
  unsigned short* scT  = (unsigned short*)(ws + (4ull << 20));
  unsigned short* E    = (unsigned short*)(ws + (20ull << 20));
  unsigned short* Wb   = (unsigned short*)(ws + (84ull << 20));
  float* sq = (float*)(ws + (84ull << 20) + (192ull << 10));
  float* T  = (float*)(ws + (84ull << 20) + (320ull << 10));

  k_prep<<<320, 256, 0, stream>>>(embW, attnW, Wb);
  k_lin<<<512, 256, 36864, stream>>>(x, Wb, embB, attnB, thrW, thrB, embb, sq, scT, T);
  k_attn<<<1024, 256, 0, stream>>>(embb, sq, T, scT, x, E, out);
}

// Round 3
// 263.144 us; speedup vs baseline: 1.4296x; 1.4296x over previous
//
#include <hip/hip_runtime.h>
#include <hip/hip_bf16.h>

// InstanceAttentionModule: B=32, H=W=32 (HW=1024), C=256, F=64, K_NEIGH=32.
// Round-3 structure (4 kernels, back to round-1 skeleton + targeted fixes):
//   k_emb      : emb = x@embW^T + b (bf16 MFMA) -> embb bf16, sq fp32 (rounded emb)
//   k_shortcut : shortcut = x@attnW^T + b -> scT bf16 [b][c][j] (transposed), Tinst
//   k_scores   : pass1: gram MFMA -> E=exp(exp(-d2)-1+mask) bf16 -> U, R rowsum
//                pass2 (fused old k_z): u=exp(relu(E/R - T)) overwrites U in place
//                (coalesced uint4), Z=rowsum(u).  E re-read is same-wave L1/L2-hot.
//   k_out      : PURE GEMM, barrier-free, no LDS: out = x + (U @ scT^T) * invZ.
//                A/B fragments loaded directly from global (both K-contiguous);
//                XCD-aware swizzle keeps scT[b] L2-resident.

typedef short bf16x8 __attribute__((ext_vector_type(8)));
typedef float f32x4 __attribute__((ext_vector_type(4)));

__device__ __forceinline__ unsigned short f2bf(float f) {
  unsigned u = __float_as_uint(f);
  u += 0x7fffu + ((u >> 16) & 1u);   // round-to-nearest-even
  return (unsigned short)(u >> 16);
}
__device__ __forceinline__ float bf2f(unsigned short h) {
  return __uint_as_float(((unsigned)h) << 16);
}
__device__ __forceinline__ unsigned pack2(float a, float b) {
  return (unsigned)f2bf(a) | ((unsigned)f2bf(b) << 16);
}
__device__ __forceinline__ f32x4 mfma16(bf16x8 a, bf16x8 b, f32x4 c) {
  return __builtin_amdgcn_mfma_f32_16x16x32_bf16(a, b, c, 0, 0, 0);
}
__device__ __forceinline__ int iabs(int v) { return v < 0 ? -v : v; }

// ---------------------------------------------------------------- k_emb
// grid 512, block 256. M-tile 64 rows x N=64 (full F). waves 2x2 (32x32 each).
__global__ __launch_bounds__(256) void k_emb(const float* __restrict__ x,
                                             const float* __restrict__ embW,
                                             const float* __restrict__ embB,
                                             unsigned short* __restrict__ embb,
                                             float* __restrict__ sq) {
  __shared__ unsigned short xs[64][40];
  __shared__ unsigned short ws[64][40];
  __shared__ float sqls[64];
  const int t = threadIdx.x;
  const int Mbase = blockIdx.x * 64;
  const int lane = t & 63, wave = t >> 6;
  const int wm = wave >> 1, wn = wave & 1;
  const int l15 = lane & 15, quad = lane >> 4;

  f32x4 acc[2][2] = {};
  for (int k0 = 0; k0 < 256; k0 += 32) {
    { // stage x tile -> bf16 LDS
      int row = t >> 2, c0 = (t & 3) * 8;
      const float* src = x + (size_t)(Mbase + row) * 256 + k0 + c0;
      float4 a = *(const float4*)src;
      float4 b = *(const float4*)(src + 4);
      uint4 p; p.x = pack2(a.x, a.y); p.y = pack2(a.z, a.w);
      p.z = pack2(b.x, b.y); p.w = pack2(b.z, b.w);
      *(uint4*)&xs[row][c0] = p;
    }
    if (t < 64) { // stage weight tile
      const float* wsrc = embW + (size_t)t * 256 + k0;
      for (int s = 0; s < 4; s++) {
        float4 a = *(const float4*)(wsrc + s * 8);
        float4 b = *(const float4*)(wsrc + s * 8 + 4);
        uint4 p; p.x = pack2(a.x, a.y); p.y = pack2(a.z, a.w);
        p.z = pack2(b.x, b.y); p.w = pack2(b.z, b.w);
        *(uint4*)&ws[t][s * 8] = p;
      }
    }
    __syncthreads();
    bf16x8 af[2], bfr[2];
    for (int rt = 0; rt < 2; rt++)
      af[rt] = *(const bf16x8*)&xs[wm * 32 + rt * 16 + l15][quad * 8];
    for (int ct = 0; ct < 2; ct++)
      bfr[ct] = *(const bf16x8*)&ws[wn * 32 + ct * 16 + l15][quad * 8];
    for (int rt = 0; rt < 2; rt++)
      for (int ct = 0; ct < 2; ct++)
        acc[rt][ct] = mfma16(af[rt], bfr[ct], acc[rt][ct]);
    __syncthreads();
  }

  if (t < 64) sqls[t] = 0.f;
  __syncthreads();
  float sp[2][4] = {};
  for (int rt = 0; rt < 2; rt++)
    for (int ct = 0; ct < 2; ct++) {
      int f = wn * 32 + ct * 16 + l15;
      float bias = embB[f];
      for (int r = 0; r < 4; r++) {
        float v = acc[rt][ct][r] + bias;
        unsigned short hb = f2bf(v);
        int rowl = wm * 32 + rt * 16 + quad * 4 + r;
        embb[(size_t)(Mbase + rowl) * 64 + f] = hb;
        float vf = bf2f(hb);
        sp[rt][r] += vf * vf;  // sq from ROUNDED emb (consistency with gram)
      }
    }
  for (int m = 8; m >= 1; m >>= 1)
    for (int rt = 0; rt < 2; rt++)
      for (int r = 0; r < 4; r++)
        sp[rt][r] += __shfl_xor(sp[rt][r], m);
  if (l15 == 0)
    for (int rt = 0; rt < 2; rt++)
      for (int r = 0; r < 4; r++)
        atomicAdd(&sqls[wm * 32 + rt * 16 + quad * 4 + r], sp[rt][r]);
  __syncthreads();
  if (t < 64) sq[Mbase + t] = sqls[t];
}

// ---------------------------------------------------------------- k_shortcut
// grid 512, block 256. M-tile 64 x N=256 full. waves 2x2 (32 rows x 128 cols).
__global__ __launch_bounds__(256) void k_shortcut(const float* __restrict__ x,
                                                  const float* __restrict__ attnW,
                                                  const float* __restrict__ attnB,
                                                  const float* __restrict__ thrW,
                                                  const float* __restrict__ thrB,
                                                  unsigned short* __restrict__ scT,
                                                  float* __restrict__ Tout) {
  __shared__ unsigned short xs[64][40];
  __shared__ unsigned short ws[256][40];
  __shared__ unsigned short St[256][72];   // [c][j], padded
  const int t = threadIdx.x;
  const int Mbase = blockIdx.x * 64;
  const int lane = t & 63, wave = t >> 6;
  const int wm = wave >> 1, wn = wave & 1;
  const int l15 = lane & 15, quad = lane >> 4;

  f32x4 acc[2][8] = {};
  for (int k0 = 0; k0 < 256; k0 += 32) {
    {
      int row = t >> 2, c0 = (t & 3) * 8;
      const float* src = x + (size_t)(Mbase + row) * 256 + k0 + c0;
      float4 a = *(const float4*)src;
      float4 b = *(const float4*)(src + 4);
      uint4 p; p.x = pack2(a.x, a.y); p.y = pack2(a.z, a.w);
      p.z = pack2(b.x, b.y); p.w = pack2(b.z, b.w);
      *(uint4*)&xs[row][c0] = p;
    }
    { // stage attn_W tile: thread t handles output-channel row t
      const float* wsrc = attnW + (size_t)t * 256 + k0;
      for (int s = 0; s < 4; s++) {
        float4 a = *(const float4*)(wsrc + s * 8);
        float4 b = *(const float4*)(wsrc + s * 8 + 4);
        uint4 p; p.x = pack2(a.x, a.y); p.y = pack2(a.z, a.w);
        p.z = pack2(b.x, b.y); p.w = pack2(b.z, b.w);
        *(uint4*)&ws[t][s * 8] = p;
      }
    }
    __syncthreads();
    bf16x8 af[2];
    for (int rt = 0; rt < 2; rt++)
      af[rt] = *(const bf16x8*)&xs[wm * 32 + rt * 16 + l15][quad * 8];
    for (int nt = 0; nt < 8; nt++) {
      bf16x8 bfr = *(const bf16x8*)&ws[wn * 128 + nt * 16 + l15][quad * 8];
      for (int rt = 0; rt < 2; rt++)
        acc[rt][nt] = mfma16(af[rt], bfr, acc[rt][nt]);
    }
    __syncthreads();
  }

  // epilogue: bias, round, transpose via LDS
  for (int rt = 0; rt < 2; rt++)
    for (int nt = 0; nt < 8; nt++) {
      int c = wn * 128 + nt * 16 + l15;
      float bias = attnB[c];
      for (int r = 0; r < 4; r++) {
        float v = acc[rt][nt][r] + bias;
        int j = wm * 32 + rt * 16 + quad * 4 + r;
        St[c][j] = f2bf(v);
      }
    }
  __syncthreads();
  const int b = Mbase >> 10, jbase = Mbase & 1023;
  { // write shortcutT[b][c][jbase..jbase+64)
    unsigned short* dst = scT + ((size_t)b * 256 + t) * 1024 + jbase;
    for (int s = 0; s < 8; s++)
      *(uint4*)(dst + s * 8) = *(const uint4*)&St[t][s * 8];
  }
  { // Tinst
    float tp = 0.f;
    int j = t >> 2, cs = (t & 3) * 64;
    for (int c = 0; c < 64; c++)
      tp += bf2f(St[cs + c][j]) * thrW[cs + c];
    tp += __shfl_xor(tp, 1);
    tp += __shfl_xor(tp, 2);
    if ((t & 3) == 0) Tout[Mbase + j] = tp + thrB[0];
  }
}

// ---------------------------------------------------------------- k_scores
// grid 512 (32 b x 16 row-blocks of 64), block 256 = 4 waves, wave owns 16 rows.
// Pass 1: gram MFMA -> E bf16 into U, R accumulated in registers.
// Pass 2 (fused k_z): re-read own strip (L1/L2-hot), u=exp(relu(E/R-T)),
//                     overwrite U in place (uint4 stores), Z=rowsum(u).
__global__ __launch_bounds__(256) void k_scores(const unsigned short* __restrict__ embb,
                                                const float* __restrict__ sq,
                                                const float* __restrict__ T,
                                                unsigned short* __restrict__ U,
                                                float* __restrict__ Z) {
  __shared__ float rbuf[64];
  const int t = threadIdx.x, lane = t & 63, wave = t >> 6;
  const int bid = blockIdx.x;
  const int b = bid >> 4, rb = (bid & 15) * 64;
  const int l15 = lane & 15, quad = lane >> 4;
  const unsigned short* eb = embb + (size_t)b * 1024 * 64;
  const int rowA = rb + wave * 16 + l15;
  bf16x8 a0 = *(const bf16x8*)(eb + (size_t)rowA * 64 + quad * 8);
  bf16x8 a1 = *(const bf16x8*)(eb + (size_t)rowA * 64 + 32 + quad * 8);
  const int rowC = rb + wave * 16 + quad * 4;
  float sqi[4]; int yi[4], xi[4];
  for (int r = 0; r < 4; r++) {
    sqi[r] = sq[b * 1024 + rowC + r];
    yi[r] = (rowC + r) >> 5; xi[r] = (rowC + r) & 31;
  }
  float rp[4] = {0.f, 0.f, 0.f, 0.f};
  for (int j0 = 0; j0 < 1024; j0 += 16) {
    const int jr = j0 + l15;
    bf16x8 b0 = *(const bf16x8*)(eb + (size_t)jr * 64 + quad * 8);
    bf16x8 b1 = *(const bf16x8*)(eb + (size_t)jr * 64 + 32 + quad * 8);
    f32x4 g = {0.f, 0.f, 0.f, 0.f};
    g = mfma16(a0, b0, g);
    g = mfma16(a1, b1, g);
    float sqj = sq[b * 1024 + jr];
    int yj = jr >> 5, xj = jr & 31;
    for (int r = 0; r < 4; r++) {
      float d2 = fmaxf(sqi[r] + sqj - 2.f * g[r], 0.f);
      int diff = iabs(yi[r] - yj) + iabs(xi[r] - xj);
      float m = (diff <= 32) ? (float)diff * (1.f / 32.f) : 0.f;
      float s = __expf(-d2) - 1.f + m;
      unsigned short h = f2bf(__expf(s));
      U[((size_t)(b * 1024 + rowC + r)) * 1024 + jr] = h;
      rp[r] += bf2f(h);   // R sums the rounded E (softmax exactly normalized)
    }
  }
  for (int m = 8; m >= 1; m >>= 1)
    for (int r = 0; r < 4; r++)
      rp[r] += __shfl_xor(rp[r], m);
  if (l15 == 0)
    for (int r = 0; r < 4; r++)
      rbuf[wave * 16 + quad * 4 + r] = rp[r];
  __syncthreads();   // drains pass-1 stores (vmcnt) + publishes rbuf

  // ---- pass 2: lane = (row, q): row = lane>>2 within strip, q = lane&3
  const int prow = lane >> 2, q = lane & 3;
  const float invR = 1.f / rbuf[wave * 16 + prow];
  unsigned short* ur = U + ((size_t)(b * 1024 + rb + wave * 16 + prow)) * 1024;
  const float* Tb = T + b * 1024;
  float z = 0.f;
  for (int jc = 0; jc < 1024; jc += 32) {
    int j = jc + q * 8;
    union { uint4 v; unsigned short s[8]; } ev;
    ev.v = *(const uint4*)(ur + j);
    float4 t0 = *(const float4*)(Tb + j);
    float4 t1 = *(const float4*)(Tb + j + 4);
    float tf[8] = {t0.x, t0.y, t0.z, t0.w, t1.x, t1.y, t1.z, t1.w};
    union { uint4 v; unsigned short s[8]; } uo;
    for (int k = 0; k < 8; k++) {
      float u = __expf(fmaxf(fmaf(bf2f(ev.s[k]), invR, -tf[k]), 0.f));
      unsigned short h = f2bf(u);
      uo.s[k] = h;
      z += bf2f(h);     // Z sums the ROUNDED u used by the GEMM
    }
    *(uint4*)(ur + j) = uo.v;
  }
  z += __shfl_xor(z, 1);
  z += __shfl_xor(z, 2);
  if (q == 0) Z[b * 1024 + rb + wave * 16 + prow] = z;
}

// ---------------------------------------------------------------- k_out
// Pure GEMM: out = x + (U @ scT^T) * invZ. grid 512, block 256 = 4 waves 2x2.
// Block tile 64 rows x 256 cols; wave 32 rows x 128 cols (2 rt x 8 nt).
// NO LDS, NO barriers: A/B frags direct from global (K-contiguous layouts).
// XCD swizzle: each XCD gets 4 whole batches -> scT[b] stays L2-resident.
__global__ __launch_bounds__(256) void k_out(const unsigned short* __restrict__ U,
                                             const float* __restrict__ Z,
                                             const unsigned short* __restrict__ scT,
                                             const float* __restrict__ x,
                                             float* __restrict__ out) {
  const int t = threadIdx.x, lane = t & 63, wave = t >> 6;
  const int wm = wave >> 1, wn = wave & 1;
  const int l15 = lane & 15, quad = lane >> 4;
  const int x8 = blockIdx.x & 7, s = blockIdx.x >> 3;   // round-robin XCD heuristic
  const int b = x8 * 4 + (s >> 4), rb = (s & 15) * 64;

  const unsigned short* Ub = U + (size_t)b * 1024 * 1024;
  const unsigned short* sb = scT + (size_t)b * 256 * 1024;
  const unsigned short* arow0 = Ub + (size_t)(rb + wm * 32 + l15) * 1024 + quad * 8;
  const unsigned short* arow1 = arow0 + 16 * 1024;
  const unsigned short* brow  = sb + (size_t)(wn * 128 + l15) * 1024 + quad * 8;

  f32x4 acc[2][8] = {};
  for (int j0 = 0; j0 < 1024; j0 += 32) {
    bf16x8 a0 = *(const bf16x8*)(arow0 + j0);
    bf16x8 a1 = *(const bf16x8*)(arow1 + j0);
    bf16x8 bf[8];
    for (int nt = 0; nt < 8; nt++)
      bf[nt] = *(const bf16x8*)(brow + (size_t)nt * 16 * 1024 + j0);
    for (int nt = 0; nt < 8; nt++) {
      acc[0][nt] = mfma16(a0, bf[nt], acc[0][nt]);
      acc[1][nt] = mfma16(a1, bf[nt], acc[1][nt]);
    }
  }

  float invZ[2][4];
  for (int rt = 0; rt < 2; rt++)
    for (int r = 0; r < 4; r++)
      invZ[rt][r] = 1.f / Z[b * 1024 + rb + wm * 32 + rt * 16 + quad * 4 + r];
  for (int rt = 0; rt < 2; rt++)
    for (int nt = 0; nt < 8; nt++) {
      int c = wn * 128 + nt * 16 + l15;
      for (int r = 0; r < 4; r++) {
        int i = rb + wm * 32 + rt * 16 + quad * 4 + r;
        size_t idx = ((size_t)(b * 1024 + i)) * 256 + c;
        out[idx] = x[idx] + acc[rt][nt][r] * invZ[rt][r];
      }
    }
}

// ---------------------------------------------------------------- launch
extern "C" void kernel_launch(void* const* d_in, const int* in_sizes, int n_in,
                              void* d_out, int out_size, void* d_ws, size_t ws_size,
                              hipStream_t stream) {
  const float* x     = (const float*)d_in[0];
  const float* embW  = (const float*)d_in[1];
  const float* embB  = (const float*)d_in[2];
  const float* attnW = (const float*)d_in[3];
  const float* attnB = (const float*)d_in[4];
  const float* thrW  = (const float*)d_in[5];
  const float* thrB  = (const float*)d_in[6];
  float* out = (float*)d_out;

  char* ws = (char*)d_ws;
  // layout: embb 4MB | scT 16MB | U 64MB | sq 128K | T 128K | Z 128K
  unsigned short* embb = (unsigned short*)(ws);
  unsigned short* scT  = (unsigned short*)(ws + (4ull << 20));
  unsigned short* U    = (unsigned short*)(ws + (20ull << 20));
  float* sq = (float*)(ws + (84ull << 20));
  float* T  = (float*)(ws + (84ull << 20) + (128ull << 10));
  float* Z  = (float*)(ws + (84ull << 20) + (256ull << 10));

  k_emb<<<512, 256, 0, stream>>>(x, embW, embB, embb, sq);
  k_shortcut<<<512, 256, 0, stream>>>(x, attnW, attnB, thrW, thrB, scT, T);
  k_scores<<<512, 256, 0, stream>>>(embb, sq, T, U, Z);
  k_out<<<512, 256, 0, stream>>>(U, Z, scT, x, out);
}

// Round 4
// 219.241 us; speedup vs baseline: 1.7159x; 1.2002x over previous
//
#include <hip/hip_runtime.h>
#include <hip/hip_bf16.h>

// InstanceAttentionModule: B=32, H=W=32 (HW=1024), C=256, F=64, K_NEIGH=32.
// Round-4: only k_out changed — rebuilt as the m97-proven GEMM structure:
//   128x128 C-tile, BK=32, global_load_lds(16B) staging of A(U) and B(scT),
//   4x4 frags/wave (16 MFMA per 8 ds_read_b128 per K-step), 16KB LDS,
//   XCD swizzle keeps each batch's scT/U tiles on one XCD's L2.
// k_emb / k_shortcut / k_scores identical to round 3 (known-good).

typedef short bf16x8 __attribute__((ext_vector_type(8)));
typedef float f32x4 __attribute__((ext_vector_type(4)));

__device__ __forceinline__ unsigned short f2bf(float f) {
  unsigned u = __float_as_uint(f);
  u += 0x7fffu + ((u >> 16) & 1u);   // round-to-nearest-even
  return (unsigned short)(u >> 16);
}
__device__ __forceinline__ float bf2f(unsigned short h) {
  return __uint_as_float(((unsigned)h) << 16);
}
__device__ __forceinline__ unsigned pack2(float a, float b) {
  return (unsigned)f2bf(a) | ((unsigned)f2bf(b) << 16);
}
__device__ __forceinline__ f32x4 mfma16(bf16x8 a, bf16x8 b, f32x4 c) {
  return __builtin_amdgcn_mfma_f32_16x16x32_bf16(a, b, c, 0, 0, 0);
}
__device__ __forceinline__ int iabs(int v) { return v < 0 ? -v : v; }
__device__ __forceinline__ void load_lds16(const void* g, void* l) {
  __builtin_amdgcn_global_load_lds(
      (const __attribute__((address_space(1))) unsigned int*)g,
      (__attribute__((address_space(3))) unsigned int*)l, 16, 0, 0);
}

// ---------------------------------------------------------------- k_emb
__global__ __launch_bounds__(256) void k_emb(const float* __restrict__ x,
                                             const float* __restrict__ embW,
                                             const float* __restrict__ embB,
                                             unsigned short* __restrict__ embb,
                                             float* __restrict__ sq) {
  __shared__ unsigned short xs[64][40];
  __shared__ unsigned short ws[64][40];
  __shared__ float sqls[64];
  const int t = threadIdx.x;
  const int Mbase = blockIdx.x * 64;
  const int lane = t & 63, wave = t >> 6;
  const int wm = wave >> 1, wn = wave & 1;
  const int l15 = lane & 15, quad = lane >> 4;

  f32x4 acc[2][2] = {};
  for (int k0 = 0; k0 < 256; k0 += 32) {
    {
      int row = t >> 2, c0 = (t & 3) * 8;
      const float* src = x + (size_t)(Mbase + row) * 256 + k0 + c0;
      float4 a = *(const float4*)src;
      float4 b = *(const float4*)(src + 4);
      uint4 p; p.x = pack2(a.x, a.y); p.y = pack2(a.z, a.w);
      p.z = pack2(b.x, b.y); p.w = pack2(b.z, b.w);
      *(uint4*)&xs[row][c0] = p;
    }
    if (t < 64) {
      const float* wsrc = embW + (size_t)t * 256 + k0;
      for (int s = 0; s < 4; s++) {
        float4 a = *(const float4*)(wsrc + s * 8);
        float4 b = *(const float4*)(wsrc + s * 8 + 4);
        uint4 p; p.x = pack2(a.x, a.y); p.y = pack2(a.z, a.w);
        p.z = pack2(b.x, b.y); p.w = pack2(b.z, b.w);
        *(uint4*)&ws[t][s * 8] = p;
      }
    }
    __syncthreads();
    bf16x8 af[2], bfr[2];
    for (int rt = 0; rt < 2; rt++)
      af[rt] = *(const bf16x8*)&xs[wm * 32 + rt * 16 + l15][quad * 8];
    for (int ct = 0; ct < 2; ct++)
      bfr[ct] = *(const bf16x8*)&ws[wn * 32 + ct * 16 + l15][quad * 8];
    for (int rt = 0; rt < 2; rt++)
      for (int ct = 0; ct < 2; ct++)
        acc[rt][ct] = mfma16(af[rt], bfr[ct], acc[rt][ct]);
    __syncthreads();
  }

  if (t < 64) sqls[t] = 0.f;
  __syncthreads();
  float sp[2][4] = {};
  for (int rt = 0; rt < 2; rt++)
    for (int ct = 0; ct < 2; ct++) {
      int f = wn * 32 + ct * 16 + l15;
      float bias = embB[f];
      for (int r = 0; r < 4; r++) {
        float v = acc[rt][ct][r] + bias;
        unsigned short hb = f2bf(v);
        int rowl = wm * 32 + rt * 16 + quad * 4 + r;
        embb[(size_t)(Mbase + rowl) * 64 + f] = hb;
        float vf = bf2f(hb);
        sp[rt][r] += vf * vf;
      }
    }
  for (int m = 8; m >= 1; m >>= 1)
    for (int rt = 0; rt < 2; rt++)
      for (int r = 0; r < 4; r++)
        sp[rt][r] += __shfl_xor(sp[rt][r], m);
  if (l15 == 0)
    for (int rt = 0; rt < 2; rt++)
      for (int r = 0; r < 4; r++)
        atomicAdd(&sqls[wm * 32 + rt * 16 + quad * 4 + r], sp[rt][r]);
  __syncthreads();
  if (t < 64) sq[Mbase + t] = sqls[t];
}

// ---------------------------------------------------------------- k_shortcut
__global__ __launch_bounds__(256) void k_shortcut(const float* __restrict__ x,
                                                  const float* __restrict__ attnW,
                                                  const float* __restrict__ attnB,
                                                  const float* __restrict__ thrW,
                                                  const float* __restrict__ thrB,
                                                  unsigned short* __restrict__ scT,
                                                  float* __restrict__ Tout) {
  __shared__ unsigned short xs[64][40];
  __shared__ unsigned short ws[256][40];
  __shared__ unsigned short St[256][72];
  const int t = threadIdx.x;
  const int Mbase = blockIdx.x * 64;
  const int lane = t & 63, wave = t >> 6;
  const int wm = wave >> 1, wn = wave & 1;
  const int l15 = lane & 15, quad = lane >> 4;

  f32x4 acc[2][8] = {};
  for (int k0 = 0; k0 < 256; k0 += 32) {
    {
      int row = t >> 2, c0 = (t & 3) * 8;
      const float* src = x + (size_t)(Mbase + row) * 256 + k0 + c0;
      float4 a = *(const float4*)src;
      float4 b = *(const float4*)(src + 4);
      uint4 p; p.x = pack2(a.x, a.y); p.y = pack2(a.z, a.w);
      p.z = pack2(b.x, b.y); p.w = pack2(b.z, b.w);
      *(uint4*)&xs[row][c0] = p;
    }
    {
      const float* wsrc = attnW + (size_t)t * 256 + k0;
      for (int s = 0; s < 4; s++) {
        float4 a = *(const float4*)(wsrc + s * 8);
        float4 b = *(const float4*)(wsrc + s * 8 + 4);
        uint4 p; p.x = pack2(a.x, a.y); p.y = pack2(a.z, a.w);
        p.z = pack2(b.x, b.y); p.w = pack2(b.z, b.w);
        *(uint4*)&ws[t][s * 8] = p;
      }
    }
    __syncthreads();
    bf16x8 af[2];
    for (int rt = 0; rt < 2; rt++)
      af[rt] = *(const bf16x8*)&xs[wm * 32 + rt * 16 + l15][quad * 8];
    for (int nt = 0; nt < 8; nt++) {
      bf16x8 bfr = *(const bf16x8*)&ws[wn * 128 + nt * 16 + l15][quad * 8];
      for (int rt = 0; rt < 2; rt++)
        acc[rt][nt] = mfma16(af[rt], bfr, acc[rt][nt]);
    }
    __syncthreads();
  }

  for (int rt = 0; rt < 2; rt++)
    for (int nt = 0; nt < 8; nt++) {
      int c = wn * 128 + nt * 16 + l15;
      float bias = attnB[c];
      for (int r = 0; r < 4; r++) {
        float v = acc[rt][nt][r] + bias;
        int j = wm * 32 + rt * 16 + quad * 4 + r;
        St[c][j] = f2bf(v);
      }
    }
  __syncthreads();
  const int b = Mbase >> 10, jbase = Mbase & 1023;
  {
    unsigned short* dst = scT + ((size_t)b * 256 + t) * 1024 + jbase;
    for (int s = 0; s < 8; s++)
      *(uint4*)(dst + s * 8) = *(const uint4*)&St[t][s * 8];
  }
  {
    float tp = 0.f;
    int j = t >> 2, cs = (t & 3) * 64;
    for (int c = 0; c < 64; c++)
      tp += bf2f(St[cs + c][j]) * thrW[cs + c];
    tp += __shfl_xor(tp, 1);
    tp += __shfl_xor(tp, 2);
    if ((t & 3) == 0) Tout[Mbase + j] = tp + thrB[0];
  }
}

// ---------------------------------------------------------------- k_scores
__global__ __launch_bounds__(256) void k_scores(const unsigned short* __restrict__ embb,
                                                const float* __restrict__ sq,
                                                const float* __restrict__ T,
                                                unsigned short* __restrict__ U,
                                                float* __restrict__ Z) {
  __shared__ float rbuf[64];
  const int t = threadIdx.x, lane = t & 63, wave = t >> 6;
  const int bid = blockIdx.x;
  const int b = bid >> 4, rb = (bid & 15) * 64;
  const int l15 = lane & 15, quad = lane >> 4;
  const unsigned short* eb = embb + (size_t)b * 1024 * 64;
  const int rowA = rb + wave * 16 + l15;
  bf16x8 a0 = *(const bf16x8*)(eb + (size_t)rowA * 64 + quad * 8);
  bf16x8 a1 = *(const bf16x8*)(eb + (size_t)rowA * 64 + 32 + quad * 8);
  const int rowC = rb + wave * 16 + quad * 4;
  float sqi[4]; int yi[4], xi[4];
  for (int r = 0; r < 4; r++) {
    sqi[r] = sq[b * 1024 + rowC + r];
    yi[r] = (rowC + r) >> 5; xi[r] = (rowC + r) & 31;
  }
  float rp[4] = {0.f, 0.f, 0.f, 0.f};
  for (int j0 = 0; j0 < 1024; j0 += 16) {
    const int jr = j0 + l15;
    bf16x8 b0 = *(const bf16x8*)(eb + (size_t)jr * 64 + quad * 8);
    bf16x8 b1 = *(const bf16x8*)(eb + (size_t)jr * 64 + 32 + quad * 8);
    f32x4 g = {0.f, 0.f, 0.f, 0.f};
    g = mfma16(a0, b0, g);
    g = mfma16(a1, b1, g);
    float sqj = sq[b * 1024 + jr];
    int yj = jr >> 5, xj = jr & 31;
    for (int r = 0; r < 4; r++) {
      float d2 = fmaxf(sqi[r] + sqj - 2.f * g[r], 0.f);
      int diff = iabs(yi[r] - yj) + iabs(xi[r] - xj);
      float m = (diff <= 32) ? (float)diff * (1.f / 32.f) : 0.f;
      float s = __expf(-d2) - 1.f + m;
      unsigned short h = f2bf(__expf(s));
      U[((size_t)(b * 1024 + rowC + r)) * 1024 + jr] = h;
      rp[r] += bf2f(h);
    }
  }
  for (int m = 8; m >= 1; m >>= 1)
    for (int r = 0; r < 4; r++)
      rp[r] += __shfl_xor(rp[r], m);
  if (l15 == 0)
    for (int r = 0; r < 4; r++)
      rbuf[wave * 16 + quad * 4 + r] = rp[r];
  __syncthreads();

  const int prow = lane >> 2, q = lane & 3;
  const float invR = 1.f / rbuf[wave * 16 + prow];
  unsigned short* ur = U + ((size_t)(b * 1024 + rb + wave * 16 + prow)) * 1024;
  const float* Tb = T + b * 1024;
  float z = 0.f;
  for (int jc = 0; jc < 1024; jc += 32) {
    int j = jc + q * 8;
    union { uint4 v; unsigned short s[8]; } ev;
    ev.v = *(const uint4*)(ur + j);
    float4 t0 = *(const float4*)(Tb + j);
    float4 t1 = *(const float4*)(Tb + j + 4);
    float tf[8] = {t0.x, t0.y, t0.z, t0.w, t1.x, t1.y, t1.z, t1.w};
    union { uint4 v; unsigned short s[8]; } uo;
    for (int k = 0; k < 8; k++) {
      float u = __expf(fmaxf(fmaf(bf2f(ev.s[k]), invR, -tf[k]), 0.f));
      unsigned short h = f2bf(u);
      uo.s[k] = h;
      z += bf2f(h);
    }
    *(uint4*)(ur + j) = uo.v;
  }
  z += __shfl_xor(z, 1);
  z += __shfl_xor(z, 2);
  if (q == 0) Z[b * 1024 + rb + wave * 16 + prow] = z;
}

// ---------------------------------------------------------------- k_out
// m97-style GEMM: out = x + (U @ scT^T) * invZ.
// grid 512 = 32 b x (8 mt x 2 nt); block 256 = 4 waves (2x2), C-tile 128x128.
// K-loop BK=32: global_load_lds 16B stages A(U) 128x32 + B(scT) 128x32 (packed,
// 64B/row) into 16KB LDS; each wave: 8 ds_read_b128 -> 16 MFMA per K-step.
// XCD swizzle: all 16 tiles of a batch on one XCD (scT + A-tiles L2-hot).
__global__ __launch_bounds__(256) void k_out(const unsigned short* __restrict__ U,
                                             const float* __restrict__ Z,
                                             const unsigned short* __restrict__ scT,
                                             const float* __restrict__ x,
                                             float* __restrict__ out) {
  __shared__ unsigned short Ab[128 * 32];   // packed row-major, 64B/row
  __shared__ unsigned short Bb[128 * 32];
  const int t = threadIdx.x, lane = t & 63, wave = t >> 6;
  const int wm = wave >> 1, wn = wave & 1;
  const int l15 = lane & 15, quad = lane >> 4;
  const int x8 = blockIdx.x & 7, s = blockIdx.x >> 3;
  const int b = x8 * 4 + (s >> 4), tile = s & 15;
  const int rb = (tile >> 1) * 128, cb = (tile & 1) * 128;

  const unsigned short* Ubase = U + (size_t)b * 1024 * 1024 + (size_t)rb * 1024;
  const unsigned short* Sbase = scT + (size_t)b * 256 * 1024 + (size_t)cb * 1024;

  // staging pattern: instr ii = s2*4 + wave covers chunks c = ii*64 + lane,
  // chunk c -> row = c>>2, col = (c&3)*8 (shorts); LDS dest = c*16 bytes.
  int c0 = wave * 64 + lane;            // s2 = 0
  int c1 = c0 + 256;                    // s2 = 1
  const int r0 = c0 >> 2, o0 = (c0 & 3) * 8;
  const int r1 = c1 >> 2, o1 = (c1 & 3) * 8;

  f32x4 acc[4][4] = {};
  for (int j0 = 0; j0 < 1024; j0 += 32) {
    load_lds16(Ubase + (size_t)r0 * 1024 + j0 + o0, Ab + c0 * 8);
    load_lds16(Ubase + (size_t)r1 * 1024 + j0 + o1, Ab + c1 * 8);
    load_lds16(Sbase + (size_t)r0 * 1024 + j0 + o0, Bb + c0 * 8);
    load_lds16(Sbase + (size_t)r1 * 1024 + j0 + o1, Bb + c1 * 8);
    __syncthreads();
    bf16x8 af[4], bf[4];
    for (int i = 0; i < 4; i++)
      af[i] = *(const bf16x8*)&Ab[(wm * 64 + i * 16 + l15) * 32 + quad * 8];
    for (int i = 0; i < 4; i++)
      bf[i] = *(const bf16x8*)&Bb[(wn * 64 + i * 16 + l15) * 32 + quad * 8];
    for (int i = 0; i < 4; i++)
      for (int j = 0; j < 4; j++)
        acc[i][j] = mfma16(af[i], bf[j], acc[i][j]);
    __syncthreads();
  }

  const int colb = cb + wn * 64;
  for (int i = 0; i < 4; i++) {
    int rowb = rb + wm * 64 + i * 16 + quad * 4;
    float iz[4];
    for (int r = 0; r < 4; r++) iz[r] = 1.f / Z[b * 1024 + rowb + r];
    for (int j = 0; j < 4; j++) {
      int c = colb + j * 16 + l15;
      for (int r = 0; r < 4; r++) {
        size_t idx = ((size_t)(b * 1024 + rowb + r)) * 256 + c;
        out[idx] = x[idx] + acc[i][j][r] * iz[r];
      }
    }
  }
}

// ---------------------------------------------------------------- launch
extern "C" void kernel_launch(void* const* d_in, const int* in_sizes, int n_in,
                              void* d_out, int out_size, void* d_ws, size_t ws_size,
                              hipStream_t stream) {
  const float* x     = (const float*)d_in[0];
  const float* embW  = (const float*)d_in[1];
  const float* embB  = (const float*)d_in[2];
  const float* attnW = (const float*)d_in[3];
  const float* attnB = (const float*)d_in[4];
  const float* thrW  = (const float*)d_in[5];
  const float* thrB  = (const float*)d_in[6];
  float* out = (float*)d_out;

  char* ws = (char*)d_ws;
  // layout: embb 4MB | scT 16MB | U 64MB | sq 128K | T 128K | Z 128K
  unsigned short* embb = (unsigned short*)(ws);
  unsigned short* scT  = (unsigned short*)(ws + (4ull << 20));
  unsigned short* U    = (unsigned short*)(ws + (20ull << 20));
  float* sq = (float*)(ws + (84ull << 20));
  float* T  = (float*)(ws + (84ull << 20) + (128ull << 10));
  float* Z  = (float*)(ws + (84ull << 20) + (256ull << 10));

  k_emb<<<512, 256, 0, stream>>>(x, embW, embB, embb, sq);
  k_shortcut<<<512, 256, 0, stream>>>(x, attnW, attnB, thrW, thrB, scT, T);
  k_scores<<<512, 256, 0, stream>>>(embb, sq, T, U, Z);
  k_out<<<512, 256, 0, stream>>>(U, Z, scT, x, out);
}

// Round 5
// 208.198 us; speedup vs baseline: 1.8069x; 1.0530x over previous
//
#include <hip/hip_runtime.h>
#include <hip/hip_bf16.h>

// InstanceAttentionModule: B=32, H=W=32 (HW=1024), C=256, F=64, K_NEIGH=32.
// Round-5: only k_scores changed — E kept in LDS (no global round-trip):
//   16-row blocks (grid 2048, 33KB LDS -> 4 blocks/CU, ~50% occupancy);
//   pass 1: 4 waves split j-range, gram MFMA -> E in LDS + R (lane-reduce + LDS atomic);
//   pass 2: u = exp(relu(E/R - T)) from LDS, written ONCE to U, Z from rounded u.
//   Removes 64MB U rewrite + 64MB U re-read vs round 4.
// k_emb / k_shortcut / k_out identical to round 4 (known-good).

typedef short bf16x8 __attribute__((ext_vector_type(8)));
typedef float f32x4 __attribute__((ext_vector_type(4)));

__device__ __forceinline__ unsigned short f2bf(float f) {
  unsigned u = __float_as_uint(f);
  u += 0x7fffu + ((u >> 16) & 1u);   // round-to-nearest-even
  return (unsigned short)(u >> 16);
}
__device__ __forceinline__ float bf2f(unsigned short h) {
  return __uint_as_float(((unsigned)h) << 16);
}
__device__ __forceinline__ unsigned pack2(float a, float b) {
  return (unsigned)f2bf(a) | ((unsigned)f2bf(b) << 16);
}
__device__ __forceinline__ f32x4 mfma16(bf16x8 a, bf16x8 b, f32x4 c) {
  return __builtin_amdgcn_mfma_f32_16x16x32_bf16(a, b, c, 0, 0, 0);
}
__device__ __forceinline__ int iabs(int v) { return v < 0 ? -v : v; }
__device__ __forceinline__ void load_lds16(const void* g, void* l) {
  __builtin_amdgcn_global_load_lds(
      (const __attribute__((address_space(1))) unsigned int*)g,
      (__attribute__((address_space(3))) unsigned int*)l, 16, 0, 0);
}

// ---------------------------------------------------------------- k_emb
__global__ __launch_bounds__(256) void k_emb(const float* __restrict__ x,
                                             const float* __restrict__ embW,
                                             const float* __restrict__ embB,
                                             unsigned short* __restrict__ embb,
                                             float* __restrict__ sq) {
  __shared__ unsigned short xs[64][40];
  __shared__ unsigned short ws[64][40];
  __shared__ float sqls[64];
  const int t = threadIdx.x;
  const int Mbase = blockIdx.x * 64;
  const int lane = t & 63, wave = t >> 6;
  const int wm = wave >> 1, wn = wave & 1;
  const int l15 = lane & 15, quad = lane >> 4;

  f32x4 acc[2][2] = {};
  for (int k0 = 0; k0 < 256; k0 += 32) {
    {
      int row = t >> 2, c0 = (t & 3) * 8;
      const float* src = x + (size_t)(Mbase + row) * 256 + k0 + c0;
      float4 a = *(const float4*)src;
      float4 b = *(const float4*)(src + 4);
      uint4 p; p.x = pack2(a.x, a.y); p.y = pack2(a.z, a.w);
      p.z = pack2(b.x, b.y); p.w = pack2(b.z, b.w);
      *(uint4*)&xs[row][c0] = p;
    }
    if (t < 64) {
      const float* wsrc = embW + (size_t)t * 256 + k0;
      for (int s = 0; s < 4; s++) {
        float4 a = *(const float4*)(wsrc + s * 8);
        float4 b = *(const float4*)(wsrc + s * 8 + 4);
        uint4 p; p.x = pack2(a.x, a.y); p.y = pack2(a.z, a.w);
        p.z = pack2(b.x, b.y); p.w = pack2(b.z, b.w);
        *(uint4*)&ws[t][s * 8] = p;
      }
    }
    __syncthreads();
    bf16x8 af[2], bfr[2];
    for (int rt = 0; rt < 2; rt++)
      af[rt] = *(const bf16x8*)&xs[wm * 32 + rt * 16 + l15][quad * 8];
    for (int ct = 0; ct < 2; ct++)
      bfr[ct] = *(const bf16x8*)&ws[wn * 32 + ct * 16 + l15][quad * 8];
    for (int rt = 0; rt < 2; rt++)
      for (int ct = 0; ct < 2; ct++)
        acc[rt][ct] = mfma16(af[rt], bfr[ct], acc[rt][ct]);
    __syncthreads();
  }

  if (t < 64) sqls[t] = 0.f;
  __syncthreads();
  float sp[2][4] = {};
  for (int rt = 0; rt < 2; rt++)
    for (int ct = 0; ct < 2; ct++) {
      int f = wn * 32 + ct * 16 + l15;
      float bias = embB[f];
      for (int r = 0; r < 4; r++) {
        float v = acc[rt][ct][r] + bias;
        unsigned short hb = f2bf(v);
        int rowl = wm * 32 + rt * 16 + quad * 4 + r;
        embb[(size_t)(Mbase + rowl) * 64 + f] = hb;
        float vf = bf2f(hb);
        sp[rt][r] += vf * vf;
      }
    }
  for (int m = 8; m >= 1; m >>= 1)
    for (int rt = 0; rt < 2; rt++)
      for (int r = 0; r < 4; r++)
        sp[rt][r] += __shfl_xor(sp[rt][r], m);
  if (l15 == 0)
    for (int rt = 0; rt < 2; rt++)
      for (int r = 0; r < 4; r++)
        atomicAdd(&sqls[wm * 32 + rt * 16 + quad * 4 + r], sp[rt][r]);
  __syncthreads();
  if (t < 64) sq[Mbase + t] = sqls[t];
}

// ---------------------------------------------------------------- k_shortcut
__global__ __launch_bounds__(256) void k_shortcut(const float* __restrict__ x,
                                                  const float* __restrict__ attnW,
                                                  const float* __restrict__ attnB,
                                                  const float* __restrict__ thrW,
                                                  const float* __restrict__ thrB,
                                                  unsigned short* __restrict__ scT,
                                                  float* __restrict__ Tout) {
  __shared__ unsigned short xs[64][40];
  __shared__ unsigned short ws[256][40];
  __shared__ unsigned short St[256][72];
  const int t = threadIdx.x;
  const int Mbase = blockIdx.x * 64;
  const int lane = t & 63, wave = t >> 6;
  const int wm = wave >> 1, wn = wave & 1;
  const int l15 = lane & 15, quad = lane >> 4;

  f32x4 acc[2][8] = {};
  for (int k0 = 0; k0 < 256; k0 += 32) {
    {
      int row = t >> 2, c0 = (t & 3) * 8;
      const float* src = x + (size_t)(Mbase + row) * 256 + k0 + c0;
      float4 a = *(const float4*)src;
      float4 b = *(const float4*)(src + 4);
      uint4 p; p.x = pack2(a.x, a.y); p.y = pack2(a.z, a.w);
      p.z = pack2(b.x, b.y); p.w = pack2(b.z, b.w);
      *(uint4*)&xs[row][c0] = p;
    }
    {
      const float* wsrc = attnW + (size_t)t * 256 + k0;
      for (int s = 0; s < 4; s++) {
        float4 a = *(const float4*)(wsrc + s * 8);
        float4 b = *(const float4*)(wsrc + s * 8 + 4);
        uint4 p; p.x = pack2(a.x, a.y); p.y = pack2(a.z, a.w);
        p.z = pack2(b.x, b.y); p.w = pack2(b.z, b.w);
        *(uint4*)&ws[t][s * 8] = p;
      }
    }
    __syncthreads();
    bf16x8 af[2];
    for (int rt = 0; rt < 2; rt++)
      af[rt] = *(const bf16x8*)&xs[wm * 32 + rt * 16 + l15][quad * 8];
    for (int nt = 0; nt < 8; nt++) {
      bf16x8 bfr = *(const bf16x8*)&ws[wn * 128 + nt * 16 + l15][quad * 8];
      for (int rt = 0; rt < 2; rt++)
        acc[rt][nt] = mfma16(af[rt], bfr, acc[rt][nt]);
    }
    __syncthreads();
  }

  for (int rt = 0; rt < 2; rt++)
    for (int nt = 0; nt < 8; nt++) {
      int c = wn * 128 + nt * 16 + l15;
      float bias = attnB[c];
      for (int r = 0; r < 4; r++) {
        float v = acc[rt][nt][r] + bias;
        int j = wm * 32 + rt * 16 + quad * 4 + r;
        St[c][j] = f2bf(v);
      }
    }
  __syncthreads();
  const int b = Mbase >> 10, jbase = Mbase & 1023;
  {
    unsigned short* dst = scT + ((size_t)b * 256 + t) * 1024 + jbase;
    for (int s = 0; s < 8; s++)
      *(uint4*)(dst + s * 8) = *(const uint4*)&St[t][s * 8];
  }
  {
    float tp = 0.f;
    int j = t >> 2, cs = (t & 3) * 64;
    for (int c = 0; c < 64; c++)
      tp += bf2f(St[cs + c][j]) * thrW[cs + c];
    tp += __shfl_xor(tp, 1);
    tp += __shfl_xor(tp, 2);
    if ((t & 3) == 0) Tout[Mbase + j] = tp + thrB[0];
  }
}

// ---------------------------------------------------------------- k_scores
// grid 2048 (32 b x 64 row-blocks of 16), block 256 = 4 waves.
// Pass 1: wave w owns j-quarter [w*256,(w+1)*256); gram MFMA over the block's
//         16 rows -> E bf16 into LDS (stride 1040, 16B-aligned rows); R via
//         lane-reduce + LDS atomicAdd.
// Pass 2: thread (row=t>>4, l=t&15): u=exp(relu(E/R - T)) from LDS, write ONCE
//         to U (coalesced 256B segments), Z = rowsum of rounded u.
__global__ __launch_bounds__(256) void k_scores(const unsigned short* __restrict__ embb,
                                                const float* __restrict__ sq,
                                                const float* __restrict__ T,
                                                unsigned short* __restrict__ U,
                                                float* __restrict__ Z) {
  __shared__ unsigned short E_lds[16 * 1040];   // 33280 B
  __shared__ float rbuf[16];
  const int t = threadIdx.x, lane = t & 63, wave = t >> 6;
  const int b = blockIdx.x >> 6, rb = (blockIdx.x & 63) * 16;
  const int l15 = lane & 15, quad = lane >> 4;
  const unsigned short* eb = embb + (size_t)b * 1024 * 64;

  if (t < 16) rbuf[t] = 0.f;

  // ---- pass 1
  const int rowA = rb + l15;   // all 16 rows, same for every wave
  bf16x8 a0 = *(const bf16x8*)(eb + (size_t)rowA * 64 + quad * 8);
  bf16x8 a1 = *(const bf16x8*)(eb + (size_t)rowA * 64 + 32 + quad * 8);
  const int rloc = quad * 4;   // local C rows quad*4 + r
  float sqi[4]; int yi[4], xi[4];
  for (int r = 0; r < 4; r++) {
    int rowg = rb + rloc + r;
    sqi[r] = sq[b * 1024 + rowg];
    yi[r] = rowg >> 5; xi[r] = rowg & 31;
  }
  const int jq = wave * 256;   // this wave's j-quarter
  float rp[4] = {0.f, 0.f, 0.f, 0.f};
  for (int j0 = jq; j0 < jq + 256; j0 += 16) {
    const int jr = j0 + l15;
    bf16x8 b0 = *(const bf16x8*)(eb + (size_t)jr * 64 + quad * 8);
    bf16x8 b1 = *(const bf16x8*)(eb + (size_t)jr * 64 + 32 + quad * 8);
    f32x4 g = {0.f, 0.f, 0.f, 0.f};
    g = mfma16(a0, b0, g);
    g = mfma16(a1, b1, g);
    float sqj = sq[b * 1024 + jr];
    int yj = jr >> 5, xj = jr & 31;
    for (int r = 0; r < 4; r++) {
      float d2 = fmaxf(sqi[r] + sqj - 2.f * g[r], 0.f);
      int diff = iabs(yi[r] - yj) + iabs(xi[r] - xj);
      float m = (diff <= 32) ? (float)diff * (1.f / 32.f) : 0.f;
      float s = __expf(-d2) - 1.f + m;
      unsigned short h = f2bf(__expf(s));
      E_lds[(rloc + r) * 1040 + jr] = h;
      rp[r] += bf2f(h);   // R sums rounded E (softmax exactly normalized)
    }
  }
  for (int m = 8; m >= 1; m >>= 1)
    for (int r = 0; r < 4; r++)
      rp[r] += __shfl_xor(rp[r], m);
  __syncthreads();               // rbuf init + all E_lds writes complete
  if (l15 == 0)
    for (int r = 0; r < 4; r++)
      atomicAdd(&rbuf[rloc + r], rp[r]);
  __syncthreads();               // R complete

  // ---- pass 2
  const int prow = t >> 4, seg = t & 15;
  const float invR = 1.f / rbuf[prow];
  const float* Tb = T + b * 1024;
  unsigned short* ur = U + ((size_t)(b * 1024 + rb + prow)) * 1024;
  float z = 0.f;
  for (int c = 0; c < 8; c++) {
    int j = c * 128 + seg * 8;
    union { bf16x8 v; unsigned short s[8]; } ev;
    ev.v = *(const bf16x8*)&E_lds[prow * 1040 + j];
    float4 t0 = *(const float4*)(Tb + j);
    float4 t1 = *(const float4*)(Tb + j + 4);
    float tf[8] = {t0.x, t0.y, t0.z, t0.w, t1.x, t1.y, t1.z, t1.w};
    union { uint4 v; unsigned short s[8]; } uo;
    for (int k = 0; k < 8; k++) {
      float u = __expf(fmaxf(fmaf(bf2f(ev.s[k]), invR, -tf[k]), 0.f));
      unsigned short h = f2bf(u);
      uo.s[k] = h;
      z += bf2f(h);     // Z sums the ROUNDED u used by the GEMM
    }
    *(uint4*)(ur + j) = uo.v;
  }
  z += __shfl_xor(z, 1);
  z += __shfl_xor(z, 2);
  z += __shfl_xor(z, 4);
  z += __shfl_xor(z, 8);
  if (seg == 0) Z[b * 1024 + rb + prow] = z;
}

// ---------------------------------------------------------------- k_out
// m97-style GEMM: out = x + (U @ scT^T) * invZ.  (unchanged from round 4)
__global__ __launch_bounds__(256) void k_out(const unsigned short* __restrict__ U,
                                             const float* __restrict__ Z,
                                             const unsigned short* __restrict__ scT,
                                             const float* __restrict__ x,
                                             float* __restrict__ out) {
  __shared__ unsigned short Ab[128 * 32];
  __shared__ unsigned short Bb[128 * 32];
  const int t = threadIdx.x, lane = t & 63, wave = t >> 6;
  const int wm = wave >> 1, wn = wave & 1;
  const int l15 = lane & 15, quad = lane >> 4;
  const int x8 = blockIdx.x & 7, s = blockIdx.x >> 3;
  const int b = x8 * 4 + (s >> 4), tile = s & 15;
  const int rb = (tile >> 1) * 128, cb = (tile & 1) * 128;

  const unsigned short* Ubase = U + (size_t)b * 1024 * 1024 + (size_t)rb * 1024;
  const unsigned short* Sbase = scT + (size_t)b * 256 * 1024 + (size_t)cb * 1024;

  int c0 = wave * 64 + lane;
  int c1 = c0 + 256;
  const int r0 = c0 >> 2, o0 = (c0 & 3) * 8;
  const int r1 = c1 >> 2, o1 = (c1 & 3) * 8;

  f32x4 acc[4][4] = {};
  for (int j0 = 0; j0 < 1024; j0 += 32) {
    load_lds16(Ubase + (size_t)r0 * 1024 + j0 + o0, Ab + c0 * 8);
    load_lds16(Ubase + (size_t)r1 * 1024 + j0 + o1, Ab + c1 * 8);
    load_lds16(Sbase + (size_t)r0 * 1024 + j0 + o0, Bb + c0 * 8);
    load_lds16(Sbase + (size_t)r1 * 1024 + j0 + o1, Bb + c1 * 8);
    __syncthreads();
    bf16x8 af[4], bf[4];
    for (int i = 0; i < 4; i++)
      af[i] = *(const bf16x8*)&Ab[(wm * 64 + i * 16 + l15) * 32 + quad * 8];
    for (int i = 0; i < 4; i++)
      bf[i] = *(const bf16x8*)&Bb[(wn * 64 + i * 16 + l15) * 32 + quad * 8];
    for (int i = 0; i < 4; i++)
      for (int j = 0; j < 4; j++)
        acc[i][j] = mfma16(af[i], bf[j], acc[i][j]);
    __syncthreads();
  }

  const int colb = cb + wn * 64;
  for (int i = 0; i < 4; i++) {
    int rowb = rb + wm * 64 + i * 16 + quad * 4;
    float iz[4];
    for (int r = 0; r < 4; r++) iz[r] = 1.f / Z[b * 1024 + rowb + r];
    for (int j = 0; j < 4; j++) {
      int c = colb + j * 16 + l15;
      for (int r = 0; r < 4; r++) {
        size_t idx = ((size_t)(b * 1024 + rowb + r)) * 256 + c;
        out[idx] = x[idx] + acc[i][j][r] * iz[r];
      }
    }
  }
}

// ---------------------------------------------------------------- launch
extern "C" void kernel_launch(void* const* d_in, const int* in_sizes, int n_in,
                              void* d_out, int out_size, void* d_ws, size_t ws_size,
                              hipStream_t stream) {
  const float* x     = (const float*)d_in[0];
  const float* embW  = (const float*)d_in[1];
  const float* embB  = (const float*)d_in[2];
  const float* attnW = (const float*)d_in[3];
  const float* attnB = (const float*)d_in[4];
  const float* thrW  = (const float*)d_in[5];
  const float* thrB  = (const float*)d_in[6];
  float* out = (float*)d_out;

  char* ws = (char*)d_ws;
  // layout: embb 4MB | scT 16MB | U 64MB | sq 128K | T 128K | Z 128K
  unsigned short* embb = (unsigned short*)(ws);
  unsigned short* scT  = (unsigned short*)(ws + (4ull << 20));
  unsigned short* U    = (unsigned short*)(ws + (20ull << 20));
  float* sq = (float*)(ws + (84ull << 20));
  float* T  = (float*)(ws + (84ull << 20) + (128ull << 10));
  float* Z  = (float*)(ws + (84ull << 20) + (256ull << 10));

  k_emb<<<512, 256, 0, stream>>>(x, embW, embB, embb, sq);
  k_shortcut<<<512, 256, 0, stream>>>(x, attnW, attnB, thrW, thrB, scT, T);
  k_scores<<<2048, 256, 0, stream>>>(embb, sq, T, U, Z);
  k_out<<<512, 256, 0, stream>>>(U, Z, scT, x, out);
}

// Round 6
// 205.101 us; speedup vs baseline: 1.8342x; 1.0151x over previous
//
#include <hip/hip_runtime.h>
#include <hip/hip_bf16.h>

// InstanceAttentionModule: B=32, H=W=32 (HW=1024), C=256, F=64, K_NEIGH=32.
// Round-6:
//   k_prep  (new): xb=bf16(x), Wb=bf16(embW||attnW), Msk63[63][63]=bf16(exp(m-1))
//                  (mask depends only on (dy,dx) -> 7.9KB L1-resident table).
//   k_emb / k_shortcut: stage from pre-converted xb/Wb (pure uint4 copies --
//                  removes per-block fp32->bf16 conversion VALU + halves fetch).
//   k_scores: mask branch replaced by Msk63 lookup: E = exp(exp(-d2)) * tab.
//   k_out: unchanged (m97 structure, known-good).
// ws overlap: xb,Wb live inside U's region (dead before k_scores writes U).

typedef short bf16x8 __attribute__((ext_vector_type(8)));
typedef float f32x4 __attribute__((ext_vector_type(4)));

__device__ __forceinline__ unsigned short f2bf(float f) {
  unsigned u = __float_as_uint(f);
  u += 0x7fffu + ((u >> 16) & 1u);   // round-to-nearest-even
  return (unsigned short)(u >> 16);
}
__device__ __forceinline__ float bf2f(unsigned short h) {
  return __uint_as_float(((unsigned)h) << 16);
}
__device__ __forceinline__ f32x4 mfma16(bf16x8 a, bf16x8 b, f32x4 c) {
  return __builtin_amdgcn_mfma_f32_16x16x32_bf16(a, b, c, 0, 0, 0);
}
__device__ __forceinline__ int iabs(int v) { return v < 0 ? -v : v; }
__device__ __forceinline__ void load_lds16(const void* g, void* l) {
  __builtin_amdgcn_global_load_lds(
      (const __attribute__((address_space(1))) unsigned int*)g,
      (__attribute__((address_space(3))) unsigned int*)l, 16, 0, 0);
}

// ---------------------------------------------------------------- k_prep
// grid 8192 x 256. Converts x (4 elems/thread), Wb, and builds Msk63.
__global__ __launch_bounds__(256) void k_prep(const float* __restrict__ x,
                                              const float* __restrict__ embW,
                                              const float* __restrict__ attnW,
                                              unsigned short* __restrict__ xb,
                                              unsigned short* __restrict__ Wb,
                                              unsigned short* __restrict__ Msk63) {
  const int tid = blockIdx.x * 256 + threadIdx.x;   // 0..2097151
  { // xb: 8,388,608 elements, 4 per thread
    float4 v = *(const float4*)(x + (size_t)tid * 4);
    ushort4 p; p.x = f2bf(v.x); p.y = f2bf(v.y); p.z = f2bf(v.z); p.w = f2bf(v.w);
    *(ushort4*)(xb + (size_t)tid * 4) = p;
  }
  if (tid < 81920) {  // Wb: embW rows 0..63, attnW rows 64..319
    float v = (tid < 16384) ? embW[tid] : attnW[tid - 16384];
    Wb[tid] = f2bf(v);
  }
  if (tid < 3969) {   // Msk63[dy+31][dx+31] = bf16(exp(m - 1))
    int dy = tid / 63 - 31, dx = tid % 63 - 31;
    int diff = iabs(dy) + iabs(dx);
    float m = (diff <= 32) ? (float)diff * (1.f / 32.f) : 0.f;
    Msk63[tid] = f2bf(__expf(m - 1.f));
  }
}

// ---------------------------------------------------------------- k_emb
// grid 512, block 256. M-tile 64 x N=64. Inputs pre-converted (xb, Wb).
__global__ __launch_bounds__(256) void k_emb(const unsigned short* __restrict__ xb,
                                             const unsigned short* __restrict__ Wb,
                                             const float* __restrict__ embB,
                                             unsigned short* __restrict__ embb,
                                             float* __restrict__ sq) {
  __shared__ unsigned short xs[64][40];
  __shared__ unsigned short ws[64][40];
  __shared__ float sqls[64];
  const int t = threadIdx.x;
  const int Mbase = blockIdx.x * 64;
  const int lane = t & 63, wave = t >> 6;
  const int wm = wave >> 1, wn = wave & 1;
  const int l15 = lane & 15, quad = lane >> 4;

  f32x4 acc[2][2] = {};
  for (int k0 = 0; k0 < 256; k0 += 32) {
    { // stage x tile (pure copy)
      int row = t >> 2, c0 = (t & 3) * 8;
      *(uint4*)&xs[row][c0] =
          *(const uint4*)(xb + (size_t)(Mbase + row) * 256 + k0 + c0);
    }
    if (t < 64) { // stage weight tile (pure copy)
      const unsigned short* wsrc = Wb + (size_t)t * 256 + k0;
      for (int s = 0; s < 4; s++)
        *(uint4*)&ws[t][s * 8] = *(const uint4*)(wsrc + s * 8);
    }
    __syncthreads();
    bf16x8 af[2], bfr[2];
    for (int rt = 0; rt < 2; rt++)
      af[rt] = *(const bf16x8*)&xs[wm * 32 + rt * 16 + l15][quad * 8];
    for (int ct = 0; ct < 2; ct++)
      bfr[ct] = *(const bf16x8*)&ws[wn * 32 + ct * 16 + l15][quad * 8];
    for (int rt = 0; rt < 2; rt++)
      for (int ct = 0; ct < 2; ct++)
        acc[rt][ct] = mfma16(af[rt], bfr[ct], acc[rt][ct]);
    __syncthreads();
  }

  if (t < 64) sqls[t] = 0.f;
  __syncthreads();
  float sp[2][4] = {};
  for (int rt = 0; rt < 2; rt++)
    for (int ct = 0; ct < 2; ct++) {
      int f = wn * 32 + ct * 16 + l15;
      float bias = embB[f];
      for (int r = 0; r < 4; r++) {
        float v = acc[rt][ct][r] + bias;
        unsigned short hb = f2bf(v);
        int rowl = wm * 32 + rt * 16 + quad * 4 + r;
        embb[(size_t)(Mbase + rowl) * 64 + f] = hb;
        float vf = bf2f(hb);
        sp[rt][r] += vf * vf;   // sq from ROUNDED emb
      }
    }
  for (int m = 8; m >= 1; m >>= 1)
    for (int rt = 0; rt < 2; rt++)
      for (int r = 0; r < 4; r++)
        sp[rt][r] += __shfl_xor(sp[rt][r], m);
  if (l15 == 0)
    for (int rt = 0; rt < 2; rt++)
      for (int r = 0; r < 4; r++)
        atomicAdd(&sqls[wm * 32 + rt * 16 + quad * 4 + r], sp[rt][r]);
  __syncthreads();
  if (t < 64) sq[Mbase + t] = sqls[t];
}

// ---------------------------------------------------------------- k_shortcut
// grid 512, block 256. M-tile 64 x N=256. Inputs pre-converted (xb, WbA).
__global__ __launch_bounds__(256) void k_shortcut(const unsigned short* __restrict__ xb,
                                                  const unsigned short* __restrict__ WbA,
                                                  const float* __restrict__ attnB,
                                                  const float* __restrict__ thrW,
                                                  const float* __restrict__ thrB,
                                                  unsigned short* __restrict__ scT,
                                                  float* __restrict__ Tout) {
  __shared__ unsigned short xs[64][40];
  __shared__ unsigned short ws[256][40];
  __shared__ unsigned short St[256][72];
  const int t = threadIdx.x;
  const int Mbase = blockIdx.x * 64;
  const int lane = t & 63, wave = t >> 6;
  const int wm = wave >> 1, wn = wave & 1;
  const int l15 = lane & 15, quad = lane >> 4;

  f32x4 acc[2][8] = {};
  for (int k0 = 0; k0 < 256; k0 += 32) {
    {
      int row = t >> 2, c0 = (t & 3) * 8;
      *(uint4*)&xs[row][c0] =
          *(const uint4*)(xb + (size_t)(Mbase + row) * 256 + k0 + c0);
    }
    {
      const unsigned short* wsrc = WbA + (size_t)t * 256 + k0;
      for (int s = 0; s < 4; s++)
        *(uint4*)&ws[t][s * 8] = *(const uint4*)(wsrc + s * 8);
    }
    __syncthreads();
    bf16x8 af[2];
    for (int rt = 0; rt < 2; rt++)
      af[rt] = *(const bf16x8*)&xs[wm * 32 + rt * 16 + l15][quad * 8];
    for (int nt = 0; nt < 8; nt++) {
      bf16x8 bfr = *(const bf16x8*)&ws[wn * 128 + nt * 16 + l15][quad * 8];
      for (int rt = 0; rt < 2; rt++)
        acc[rt][nt] = mfma16(af[rt], bfr, acc[rt][nt]);
    }
    __syncthreads();
  }

  for (int rt = 0; rt < 2; rt++)
    for (int nt = 0; nt < 8; nt++) {
      int c = wn * 128 + nt * 16 + l15;
      float bias = attnB[c];
      for (int r = 0; r < 4; r++) {
        float v = acc[rt][nt][r] + bias;
        int j = wm * 32 + rt * 16 + quad * 4 + r;
        St[c][j] = f2bf(v);
      }
    }
  __syncthreads();
  const int b = Mbase >> 10, jbase = Mbase & 1023;
  {
    unsigned short* dst = scT + ((size_t)b * 256 + t) * 1024 + jbase;
    for (int s = 0; s < 8; s++)
      *(uint4*)(dst + s * 8) = *(const uint4*)&St[t][s * 8];
  }
  {
    float tp = 0.f;
    int j = t >> 2, cs = (t & 3) * 64;
    for (int c = 0; c < 64; c++)
      tp += bf2f(St[cs + c][j]) * thrW[cs + c];
    tp += __shfl_xor(tp, 1);
    tp += __shfl_xor(tp, 2);
    if ((t & 3) == 0) Tout[Mbase + j] = tp + thrB[0];
  }
}

// ---------------------------------------------------------------- k_scores
// grid 2048 (32 b x 64 row-blocks of 16), block 256 = 4 waves.
// Pass 1: gram MFMA -> E = exp(exp(-d2)) * Msk63[dy][dx] -> LDS + R.
// Pass 2: u = exp(relu(E/R - T)) -> U (single write), Z = rowsum(rounded u).
__global__ __launch_bounds__(256) void k_scores(const unsigned short* __restrict__ embb,
                                                const float* __restrict__ sq,
                                                const float* __restrict__ T,
                                                const unsigned short* __restrict__ Msk63,
                                                unsigned short* __restrict__ U,
                                                float* __restrict__ Z) {
  __shared__ unsigned short E_lds[16 * 1040];   // 33280 B
  __shared__ float rbuf[16];
  const int t = threadIdx.x, lane = t & 63, wave = t >> 6;
  const int b = blockIdx.x >> 6, rb = (blockIdx.x & 63) * 16;
  const int l15 = lane & 15, quad = lane >> 4;
  const unsigned short* eb = embb + (size_t)b * 1024 * 64;

  if (t < 16) rbuf[t] = 0.f;

  // ---- pass 1
  const int rowA = rb + l15;
  bf16x8 a0 = *(const bf16x8*)(eb + (size_t)rowA * 64 + quad * 8);
  bf16x8 a1 = *(const bf16x8*)(eb + (size_t)rowA * 64 + 32 + quad * 8);
  const int rloc = quad * 4;
  float nsqi[4]; int yi[4], xi[4];
  for (int r = 0; r < 4; r++) {
    int rowg = rb + rloc + r;
    nsqi[r] = -sq[b * 1024 + rowg];
    yi[r] = rowg >> 5; xi[r] = rowg & 31;
  }
  const int jq = wave * 256;
  float rp[4] = {0.f, 0.f, 0.f, 0.f};
  for (int j0 = jq; j0 < jq + 256; j0 += 16) {
    const int jr = j0 + l15;
    bf16x8 b0 = *(const bf16x8*)(eb + (size_t)jr * 64 + quad * 8);
    bf16x8 b1 = *(const bf16x8*)(eb + (size_t)jr * 64 + 32 + quad * 8);
    f32x4 g = {0.f, 0.f, 0.f, 0.f};
    g = mfma16(a0, b0, g);
    g = mfma16(a1, b1, g);
    float sqj = sq[b * 1024 + jr];
    int yj = jr >> 5, xj = jr & 31;
    for (int r = 0; r < 4; r++) {
      // -d2 = 2g - sqi - sqj, clamped to <= 0
      float w = fminf(fmaf(2.f, g[r], nsqi[r] - sqj), 0.f);
      float v = __expf(w);                       // exp(-d2) in (0,1]
      int idx = (yi[r] - yj) * 63 + (xi[r] - xj) + 1984;  // (dy+31)*63+(dx+31)
      float e = __expf(v) * bf2f(Msk63[idx]);    // exp(v-1+m)
      unsigned short h = f2bf(e);
      E_lds[(rloc + r) * 1040 + jr] = h;
      rp[r] += bf2f(h);   // R sums rounded E
    }
  }
  for (int m = 8; m >= 1; m >>= 1)
    for (int r = 0; r < 4; r++)
      rp[r] += __shfl_xor(rp[r], m);
  __syncthreads();
  if (l15 == 0)
    for (int r = 0; r < 4; r++)
      atomicAdd(&rbuf[rloc + r], rp[r]);
  __syncthreads();

  // ---- pass 2
  const int prow = t >> 4, seg = t & 15;
  const float invR = 1.f / rbuf[prow];
  const float* Tb = T + b * 1024;
  unsigned short* ur = U + ((size_t)(b * 1024 + rb + prow)) * 1024;
  float z = 0.f;
  for (int c = 0; c < 8; c++) {
    int j = c * 128 + seg * 8;
    union { bf16x8 v; unsigned short s[8]; } ev;
    ev.v = *(const bf16x8*)&E_lds[prow * 1040 + j];
    float4 t0 = *(const float4*)(Tb + j);
    float4 t1 = *(const float4*)(Tb + j + 4);
    float tf[8] = {t0.x, t0.y, t0.z, t0.w, t1.x, t1.y, t1.z, t1.w};
    union { uint4 v; unsigned short s[8]; } uo;
    for (int k = 0; k < 8; k++) {
      float u = __expf(fmaxf(fmaf(bf2f(ev.s[k]), invR, -tf[k]), 0.f));
      unsigned short h = f2bf(u);
      uo.s[k] = h;
      z += bf2f(h);   // Z sums the ROUNDED u
    }
    *(uint4*)(ur + j) = uo.v;
  }
  z += __shfl_xor(z, 1);
  z += __shfl_xor(z, 2);
  z += __shfl_xor(z, 4);
  z += __shfl_xor(z, 8);
  if (seg == 0) Z[b * 1024 + rb + prow] = z;
}

// ---------------------------------------------------------------- k_out
// m97-style GEMM: out = x + (U @ scT^T) * invZ.  (unchanged)
__global__ __launch_bounds__(256) void k_out(const unsigned short* __restrict__ U,
                                             const float* __restrict__ Z,
                                             const unsigned short* __restrict__ scT,
                                             const float* __restrict__ x,
                                             float* __restrict__ out) {
  __shared__ unsigned short Ab[128 * 32];
  __shared__ unsigned short Bb[128 * 32];
  const int t = threadIdx.x, lane = t & 63, wave = t >> 6;
  const int wm = wave >> 1, wn = wave & 1;
  const int l15 = lane & 15, quad = lane >> 4;
  const int x8 = blockIdx.x & 7, s = blockIdx.x >> 3;
  const int b = x8 * 4 + (s >> 4), tile = s & 15;
  const int rb = (tile >> 1) * 128, cb = (tile & 1) * 128;

  const unsigned short* Ubase = U + (size_t)b * 1024 * 1024 + (size_t)rb * 1024;
  const unsigned short* Sbase = scT + (size_t)b * 256 * 1024 + (size_t)cb * 1024;

  int c0 = wave * 64 + lane;
  int c1 = c0 + 256;
  const int r0 = c0 >> 2, o0 = (c0 & 3) * 8;
  const int r1 = c1 >> 2, o1 = (c1 & 3) * 8;

  f32x4 acc[4][4] = {};
  for (int j0 = 0; j0 < 1024; j0 += 32) {
    load_lds16(Ubase + (size_t)r0 * 1024 + j0 + o0, Ab + c0 * 8);
    load_lds16(Ubase + (size_t)r1 * 1024 + j0 + o1, Ab + c1 * 8);
    load_lds16(Sbase + (size_t)r0 * 1024 + j0 + o0, Bb + c0 * 8);
    load_lds16(Sbase + (size_t)r1 * 1024 + j0 + o1, Bb + c1 * 8);
    __syncthreads();
    bf16x8 af[4], bf[4];
    for (int i = 0; i < 4; i++)
      af[i] = *(const bf16x8*)&Ab[(wm * 64 + i * 16 + l15) * 32 + quad * 8];
    for (int i = 0; i < 4; i++)
      bf[i] = *(const bf16x8*)&Bb[(wn * 64 + i * 16 + l15) * 32 + quad * 8];
    for (int i = 0; i < 4; i++)
      for (int j = 0; j < 4; j++)
        acc[i][j] = mfma16(af[i], bf[j], acc[i][j]);
    __syncthreads();
  }

  const int colb = cb + wn * 64;
  for (int i = 0; i < 4; i++) {
    int rowb = rb + wm * 64 + i * 16 + quad * 4;
    float iz[4];
    for (int r = 0; r < 4; r++) iz[r] = 1.f / Z[b * 1024 + rowb + r];
    for (int j = 0; j < 4; j++) {
      int c = colb + j * 16 + l15;
      for (int r = 0; r < 4; r++) {
        size_t idx = ((size_t)(b * 1024 + rowb + r)) * 256 + c;
        out[idx] = x[idx] + acc[i][j][r] * iz[r];
      }
    }
  }
}

// ---------------------------------------------------------------- launch
extern "C" void kernel_launch(void* const* d_in, const int* in_sizes, int n_in,
                              void* d_out, int out_size, void* d_ws, size_t ws_size,
                              hipStream_t stream) {
  const float* x     = (const float*)d_in[0];
  const float* embW  = (const float*)d_in[1];
  const float* embB  = (const float*)d_in[2];
  const float* attnW = (const float*)d_in[3];
  const float* attnB = (const float*)d_in[4];
  const float* thrW  = (const float*)d_in[5];
  const float* thrB  = (const float*)d_in[6];
  float* out = (float*)d_out;

  char* ws = (char*)d_ws;
  // layout: embb 4MB | scT 16MB | U 64MB | sq/T/Z/Msk63 tail
  // xb (16MB) and Wb (160KB) OVERLAP U: dead before k_scores writes U.
  unsigned short* embb = (unsigned short*)(ws);
  unsigned short* scT  = (unsigned short*)(ws + (4ull << 20));
  unsigned short* U    = (unsigned short*)(ws + (20ull << 20));
  unsigned short* xb   = (unsigned short*)(ws + (20ull << 20));   // overlap
  unsigned short* Wb   = (unsigned short*)(ws + (36ull << 20));   // overlap
  float* sq = (float*)(ws + (84ull << 20));
  float* T  = (float*)(ws + (84ull << 20) + (128ull << 10));
  float* Z  = (float*)(ws + (84ull << 20) + (256ull << 10));
  unsigned short* Msk63 = (unsigned short*)(ws + (84ull << 20) + (384ull << 10));

  k_prep<<<8192, 256, 0, stream>>>(x, embW, attnW, xb, Wb, Msk63);
  k_emb<<<512, 256, 0, stream>>>(xb, Wb, embB, embb, sq);
  k_shortcut<<<512, 256, 0, stream>>>(xb, Wb + 16384, attnB, thrW, thrB, scT, T);
  k_scores<<<2048, 256, 0, stream>>>(embb, sq, T, Msk63, U, Z);
  k_out<<<512, 256, 0, stream>>>(U, Z, scT, x, out);
}

// Round 7
// 198.794 us; speedup vs baseline: 1.8924x; 1.0317x over previous
//
#include <hip/hip_runtime.h>
#include <hip/hip_bf16.h>

// InstanceAttentionModule: B=32, H=W=32 (HW=1024), C=256, F=64, K_NEIGH=32.
// Round-7 (4 kernels):
//   k_prep   : xb = bf16(x), Wb = bf16(embW||attnW)
//   k_lin    : FUSED emb+shortcut GEMM (N=320) — one x staging, LDS-staged Wb;
//              epilogues: embb bf16 + sq (rounded emb), scT [b][c][j] + Tinst
//   k_scores : gram MFMA -> E = exp(exp(-d2)) * mtab[diff] (mtab in LDS — fixes
//              round-6's global-gather regression) -> E in LDS + R;
//              pass 2: u = exp(relu(E/R - T)) -> U (single write), Z
//   k_out    : m97-style GEMM out = x + (U @ scT^T)*invZ (unchanged, known-good)

typedef short bf16x8 __attribute__((ext_vector_type(8)));
typedef float f32x4 __attribute__((ext_vector_type(4)));

__device__ __forceinline__ unsigned short f2bf(float f) {
  unsigned u = __float_as_uint(f);
  u += 0x7fffu + ((u >> 16) & 1u);   // round-to-nearest-even
  return (unsigned short)(u >> 16);
}
__device__ __forceinline__ float bf2f(unsigned short h) {
  return __uint_as_float(((unsigned)h) << 16);
}
__device__ __forceinline__ f32x4 mfma16(bf16x8 a, bf16x8 b, f32x4 c) {
  return __builtin_amdgcn_mfma_f32_16x16x32_bf16(a, b, c, 0, 0, 0);
}
__device__ __forceinline__ int iabs(int v) { return v < 0 ? -v : v; }
__device__ __forceinline__ void load_lds16(const void* g, void* l) {
  __builtin_amdgcn_global_load_lds(
      (const __attribute__((address_space(1))) unsigned int*)g,
      (__attribute__((address_space(3))) unsigned int*)l, 16, 0, 0);
}

// ---------------------------------------------------------------- k_prep
// grid 8192 x 256: xb (4 elems/thread) + Wb (embW rows 0..63, attnW 64..319).
__global__ __launch_bounds__(256) void k_prep(const float* __restrict__ x,
                                              const float* __restrict__ embW,
                                              const float* __restrict__ attnW,
                                              unsigned short* __restrict__ xb,
                                              unsigned short* __restrict__ Wb) {
  const int tid = blockIdx.x * 256 + threadIdx.x;   // 0..2097151
  {
    float4 v = *(const float4*)(x + (size_t)tid * 4);
    ushort4 p; p.x = f2bf(v.x); p.y = f2bf(v.y); p.z = f2bf(v.z); p.w = f2bf(v.w);
    *(ushort4*)(xb + (size_t)tid * 4) = p;
  }
  if (tid < 81920) {
    float v = (tid < 16384) ? embW[tid] : attnW[tid - 16384];
    Wb[tid] = f2bf(v);
  }
}

// ---------------------------------------------------------------- k_lin
// Fused emb+shortcut. grid 512 (64-row M-tiles), block 256 = 4 waves (2x2).
// Wave tile: 32 rows x 160 cols of the N=320 concatenated output.
// K-loop BK=32: xs 64x32 + ws 320x32 staged in LDS (pure uint4 copies from
// xb/Wb); per wave 20 MFMA : 12 ds_read_b128 per K-step.
__global__ __launch_bounds__(256) void k_lin(const unsigned short* __restrict__ xb,
                                             const unsigned short* __restrict__ Wb,
                                             const float* __restrict__ embB,
                                             const float* __restrict__ attnB,
                                             const float* __restrict__ thrW,
                                             const float* __restrict__ thrB,
                                             unsigned short* __restrict__ embb,
                                             float* __restrict__ sq,
                                             unsigned short* __restrict__ scT,
                                             float* __restrict__ Tout) {
  __shared__ union {
    struct { unsigned short xs[64][40]; unsigned short ws[320][40]; } a;
    unsigned short St[256][72];
  } sm;
  const int t = threadIdx.x;
  const int Mbase = blockIdx.x * 64;
  const int lane = t & 63, wave = t >> 6;
  const int wm = wave >> 1, wn = wave & 1;
  const int l15 = lane & 15, quad = lane >> 4;

  f32x4 acc[2][10] = {};
  for (int k0 = 0; k0 < 256; k0 += 32) {
    { // stage x tile (64x32)
      int row = t >> 2, c0 = (t & 3) * 8;
      *(uint4*)&sm.a.xs[row][c0] =
          *(const uint4*)(xb + (size_t)(Mbase + row) * 256 + k0 + c0);
    }
    { // stage weight tile (320x32): thread t -> row t; t<64 also row 256+t
      const unsigned short* wsrc = Wb + (size_t)t * 256 + k0;
      for (int s = 0; s < 4; s++)
        *(uint4*)&sm.a.ws[t][s * 8] = *(const uint4*)(wsrc + s * 8);
      if (t < 64) {
        const unsigned short* wsrc2 = Wb + (size_t)(256 + t) * 256 + k0;
        for (int s = 0; s < 4; s++)
          *(uint4*)&sm.a.ws[256 + t][s * 8] = *(const uint4*)(wsrc2 + s * 8);
      }
    }
    __syncthreads();
    bf16x8 af[2];
    af[0] = *(const bf16x8*)&sm.a.xs[wm * 32 + l15][quad * 8];
    af[1] = *(const bf16x8*)&sm.a.xs[wm * 32 + 16 + l15][quad * 8];
    for (int nt = 0; nt < 10; nt++) {
      bf16x8 bfr = *(const bf16x8*)&sm.a.ws[wn * 160 + nt * 16 + l15][quad * 8];
      acc[0][nt] = mfma16(af[0], bfr, acc[0][nt]);
      acc[1][nt] = mfma16(af[1], bfr, acc[1][nt]);
    }
    __syncthreads();
  }

  // emb epilogue: wn==0 waves own n<64 (nt 0..3); sq from ROUNDED emb.
  if (wn == 0) {
    float sp[2][4] = {{0.f,0.f,0.f,0.f},{0.f,0.f,0.f,0.f}};
    for (int rt = 0; rt < 2; rt++)
      for (int nt = 0; nt < 4; nt++) {
        int n = nt * 16 + l15;
        float bias = embB[n];
        for (int r = 0; r < 4; r++) {
          float v = acc[rt][nt][r] + bias;
          unsigned short hb = f2bf(v);
          int row = wm * 32 + rt * 16 + quad * 4 + r;
          embb[(size_t)(Mbase + row) * 64 + n] = hb;
          float vf = bf2f(hb);
          sp[rt][r] += vf * vf;
        }
      }
    for (int m = 8; m >= 1; m >>= 1)
      for (int rt = 0; rt < 2; rt++)
        for (int r = 0; r < 4; r++)
          sp[rt][r] += __shfl_xor(sp[rt][r], m);
    if (l15 == 0)
      for (int rt = 0; rt < 2; rt++)
        for (int r = 0; r < 4; r++)
          sq[Mbase + wm * 32 + rt * 16 + quad * 4 + r] = sp[rt][r];
  }

  // shortcut epilogue -> St transpose buffer (St aliases xs/ws; loop barrier done)
  for (int rt = 0; rt < 2; rt++)
    for (int nt = 0; nt < 10; nt++) {
      int n = wn * 160 + nt * 16 + l15;
      if (n < 64) continue;
      int c = n - 64;
      float bias = attnB[c];
      for (int r = 0; r < 4; r++) {
        float v = acc[rt][nt][r] + bias;
        sm.St[c][wm * 32 + rt * 16 + quad * 4 + r] = f2bf(v);
      }
    }
  __syncthreads();

  const int b = Mbase >> 10, jbase = Mbase & 1023;
  { // coalesced write of scT[b][c][jbase..jbase+64)
    unsigned short* dst = scT + ((size_t)b * 256 + t) * 1024 + jbase;
    for (int s = 0; s < 8; s++)
      *(uint4*)(dst + s * 8) = *(const uint4*)&sm.St[t][s * 8];
  }
  { // Tinst
    float tp = 0.f;
    int j = t >> 2, cs = (t & 3) * 64;
    for (int c = 0; c < 64; c++)
      tp += bf2f(sm.St[cs + c][j]) * thrW[cs + c];
    tp += __shfl_xor(tp, 1);
    tp += __shfl_xor(tp, 2);
    if ((t & 3) == 0) Tout[Mbase + j] = tp + thrB[0];
  }
}

// ---------------------------------------------------------------- k_scores
// grid 2048 (32 b x 64 row-blocks of 16), block 256 = 4 waves.
// Pass 1: gram MFMA -> E = exp(exp(-d2)) * mtab[diff] (mtab LDS) -> E_lds + R.
// Pass 2: u = exp(relu(E/R - T)) -> U (single write), Z = rowsum(rounded u).
__global__ __launch_bounds__(256) void k_scores(const unsigned short* __restrict__ embb,
                                                const float* __restrict__ sq,
                                                const float* __restrict__ T,
                                                unsigned short* __restrict__ U,
                                                float* __restrict__ Z) {
  __shared__ unsigned short E_lds[16 * 1040];   // 33280 B
  __shared__ float rbuf[16];
  __shared__ float mtab[64];                    // exp(m(diff) - 1), diff 0..62
  const int t = threadIdx.x, lane = t & 63, wave = t >> 6;
  const int b = blockIdx.x >> 6, rb = (blockIdx.x & 63) * 16;
  const int l15 = lane & 15, quad = lane >> 4;
  const unsigned short* eb = embb + (size_t)b * 1024 * 64;

  if (t < 16) rbuf[t] = 0.f;
  if (t < 64) {
    float m = (t <= 32) ? (float)t * (1.f / 32.f) : 0.f;
    mtab[t] = __expf(m - 1.f);
  }
  __syncthreads();   // mtab + rbuf visible

  // ---- pass 1
  const int rowA = rb + l15;
  bf16x8 a0 = *(const bf16x8*)(eb + (size_t)rowA * 64 + quad * 8);
  bf16x8 a1 = *(const bf16x8*)(eb + (size_t)rowA * 64 + 32 + quad * 8);
  const int rloc = quad * 4;
  float nsqi[4]; int yi[4], xi[4];
  for (int r = 0; r < 4; r++) {
    int rowg = rb + rloc + r;
    nsqi[r] = -sq[b * 1024 + rowg];
    yi[r] = rowg >> 5; xi[r] = rowg & 31;
  }
  const int jq = wave * 256;
  float rp[4] = {0.f, 0.f, 0.f, 0.f};
  for (int j0 = jq; j0 < jq + 256; j0 += 16) {
    const int jr = j0 + l15;
    bf16x8 b0 = *(const bf16x8*)(eb + (size_t)jr * 64 + quad * 8);
    bf16x8 b1 = *(const bf16x8*)(eb + (size_t)jr * 64 + 32 + quad * 8);
    f32x4 g = {0.f, 0.f, 0.f, 0.f};
    g = mfma16(a0, b0, g);
    g = mfma16(a1, b1, g);
    float sqj = sq[b * 1024 + jr];
    int yj = jr >> 5, xj = jr & 31;
    for (int r = 0; r < 4; r++) {
      float w = fminf(fmaf(2.f, g[r], nsqi[r] - sqj), 0.f);  // -d2, <= 0
      float v = __expf(w);                                    // exp(-d2)
      int diff = iabs(yi[r] - yj) + iabs(xi[r] - xj);
      float e = __expf(v) * mtab[diff];                       // exp(v - 1 + m)
      E_lds[(rloc + r) * 1040 + jr] = f2bf(e);
      rp[r] += e;   // unrounded sum: rel err ~1e-4 on R, damped to ~1e-7 in u
    }
  }
  for (int m = 8; m >= 1; m >>= 1)
    for (int r = 0; r < 4; r++)
      rp[r] += __shfl_xor(rp[r], m);
  __syncthreads();   // E_lds writes complete
  if (l15 == 0)
    for (int r = 0; r < 4; r++)
      atomicAdd(&rbuf[rloc + r], rp[r]);
  __syncthreads();   // R complete

  // ---- pass 2
  const int prow = t >> 4, seg = t & 15;
  const float invR = 1.f / rbuf[prow];
  const float* Tb = T + b * 1024;
  unsigned short* ur = U + ((size_t)(b * 1024 + rb + prow)) * 1024;
  float z = 0.f;
  for (int c = 0; c < 8; c++) {
    int j = c * 128 + seg * 8;
    union { bf16x8 v; unsigned short s[8]; } ev;
    ev.v = *(const bf16x8*)&E_lds[prow * 1040 + j];
    float4 t0 = *(const float4*)(Tb + j);
    float4 t1 = *(const float4*)(Tb + j + 4);
    float tf[8] = {t0.x, t0.y, t0.z, t0.w, t1.x, t1.y, t1.z, t1.w};
    union { uint4 v; unsigned short s[8]; } uo;
    for (int k = 0; k < 8; k++) {
      float u = __expf(fmaxf(fmaf(bf2f(ev.s[k]), invR, -tf[k]), 0.f));
      unsigned short h = f2bf(u);
      uo.s[k] = h;
      z += bf2f(h);   // Z sums the ROUNDED u used by the GEMM
    }
    *(uint4*)(ur + j) = uo.v;
  }
  z += __shfl_xor(z, 1);
  z += __shfl_xor(z, 2);
  z += __shfl_xor(z, 4);
  z += __shfl_xor(z, 8);
  if (seg == 0) Z[b * 1024 + rb + prow] = z;
}

// ---------------------------------------------------------------- k_out
// m97-style GEMM: out = x + (U @ scT^T) * invZ.  (unchanged)
__global__ __launch_bounds__(256) void k_out(const unsigned short* __restrict__ U,
                                             const float* __restrict__ Z,
                                             const unsigned short* __restrict__ scT,
                                             const float* __restrict__ x,
                                             float* __restrict__ out) {
  __shared__ unsigned short Ab[128 * 32];
  __shared__ unsigned short Bb[128 * 32];
  const int t = threadIdx.x, lane = t & 63, wave = t >> 6;
  const int wm = wave >> 1, wn = wave & 1;
  const int l15 = lane & 15, quad = lane >> 4;
  const int x8 = blockIdx.x & 7, s = blockIdx.x >> 3;
  const int b = x8 * 4 + (s >> 4), tile = s & 15;
  const int rb = (tile >> 1) * 128, cb = (tile & 1) * 128;

  const unsigned short* Ubase = U + (size_t)b * 1024 * 1024 + (size_t)rb * 1024;
  const unsigned short* Sbase = scT + (size_t)b * 256 * 1024 + (size_t)cb * 1024;

  int c0 = wave * 64 + lane;
  int c1 = c0 + 256;
  const int r0 = c0 >> 2, o0 = (c0 & 3) * 8;
  const int r1 = c1 >> 2, o1 = (c1 & 3) * 8;

  f32x4 acc[4][4] = {};
  for (int j0 = 0; j0 < 1024; j0 += 32) {
    load_lds16(Ubase + (size_t)r0 * 1024 + j0 + o0, Ab + c0 * 8);
    load_lds16(Ubase + (size_t)r1 * 1024 + j0 + o1, Ab + c1 * 8);
    load_lds16(Sbase + (size_t)r0 * 1024 + j0 + o0, Bb + c0 * 8);
    load_lds16(Sbase + (size_t)r1 * 1024 + j0 + o1, Bb + c1 * 8);
    __syncthreads();
    bf16x8 af[4], bf[4];
    for (int i = 0; i < 4; i++)
      af[i] = *(const bf16x8*)&Ab[(wm * 64 + i * 16 + l15) * 32 + quad * 8];
    for (int i = 0; i < 4; i++)
      bf[i] = *(const bf16x8*)&Bb[(wn * 64 + i * 16 + l15) * 32 + quad * 8];
    for (int i = 0; i < 4; i++)
      for (int j = 0; j < 4; j++)
        acc[i][j] = mfma16(af[i], bf[j], acc[i][j]);
    __syncthreads();
  }

  const int colb = cb + wn * 64;
  for (int i = 0; i < 4; i++) {
    int rowb = rb + wm * 64 + i * 16 + quad * 4;
    float iz[4];
    for (int r = 0; r < 4; r++) iz[r] = 1.f / Z[b * 1024 + rowb + r];
    for (int j = 0; j < 4; j++) {
      int c = colb + j * 16 + l15;
      for (int r = 0; r < 4; r++) {
        size_t idx = ((size_t)(b * 1024 + rowb + r)) * 256 + c;
        out[idx] = x[idx] + acc[i][j][r] * iz[r];
      }
    }
  }
}

// ---------------------------------------------------------------- launch
extern "C" void kernel_launch(void* const* d_in, const int* in_sizes, int n_in,
                              void* d_out, int out_size, void* d_ws, size_t ws_size,
                              hipStream_t stream) {
  const float* x     = (const float*)d_in[0];
  const float* embW  = (const float*)d_in[1];
  const float* embB  = (const float*)d_in[2];
  const float* attnW = (const float*)d_in[3];
  const float* attnB = (const float*)d_in[4];
  const float* thrW  = (const float*)d_in[5];
  const float* thrB  = (const float*)d_in[6];
  float* out = (float*)d_out;

  char* ws = (char*)d_ws;
  // layout: embb 4MB | scT 16MB | U 64MB | sq/T/Z tail
  // xb (16MB) and Wb (160KB) OVERLAP U: dead before k_scores writes U.
  unsigned short* embb = (unsigned short*)(ws);
  unsigned short* scT  = (unsigned short*)(ws + (4ull << 20));
  unsigned short* U    = (unsigned short*)(ws + (20ull << 20));
  unsigned short* xb   = (unsigned short*)(ws + (20ull << 20));   // overlap
  unsigned short* Wb   = (unsigned short*)(ws + (36ull << 20));   // overlap
  float* sq = (float*)(ws + (84ull << 20));
  float* T  = (float*)(ws + (84ull << 20) + (128ull << 10));
  float* Z  = (float*)(ws + (84ull << 20) + (256ull << 10));

  k_prep<<<8192, 256, 0, stream>>>(x, embW, attnW, xb, Wb);
  k_lin<<<512, 256, 0, stream>>>(xb, Wb, embB, attnB, thrW, thrB, embb, sq, scT, T);
  k_scores<<<2048, 256, 0, stream>>>(embb, sq, T, U, Z);
  k_out<<<512, 256, 0, stream>>>(U, Z, scT, x, out);
}

// Round 8
// 195.407 us; speedup vs baseline: 1.9252x; 1.0173x over previous
//
#include <hip/hip_runtime.h>
#include <hip/hip_bf16.h>

// InstanceAttentionModule: B=32, H=W=32 (HW=1024), C=256, F=64, K_NEIGH=32.
// Round-8:
//   k_prep   : Wb = bf16(embW||attnW) ONLY (x pre-conversion removed: xb was
//              read exactly once by k_lin -> the round-trip was a pure loss)
//   k_lin    : fused emb+shortcut GEMM (N=320); x staged from fp32 inline
//   k_scores : 512-thread blocks (8 waves per 16-row strip, wave = j-eighth):
//              same 33.3KB LDS now carries 8 waves -> 4 blk/CU = 32 waves/CU
//              (was 16) — attacks the 36%-occupancy latency bound head-on
//   k_out    : m97-style GEMM out = x + (U @ scT^T)*invZ (unchanged)

typedef short bf16x8 __attribute__((ext_vector_type(8)));
typedef float f32x4 __attribute__((ext_vector_type(4)));

__device__ __forceinline__ unsigned short f2bf(float f) {
  unsigned u = __float_as_uint(f);
  u += 0x7fffu + ((u >> 16) & 1u);   // round-to-nearest-even
  return (unsigned short)(u >> 16);
}
__device__ __forceinline__ float bf2f(unsigned short h) {
  return __uint_as_float(((unsigned)h) << 16);
}
__device__ __forceinline__ unsigned pack2(float a, float b) {
  return (unsigned)f2bf(a) | ((unsigned)f2bf(b) << 16);
}
__device__ __forceinline__ f32x4 mfma16(bf16x8 a, bf16x8 b, f32x4 c) {
  return __builtin_amdgcn_mfma_f32_16x16x32_bf16(a, b, c, 0, 0, 0);
}
__device__ __forceinline__ int iabs(int v) { return v < 0 ? -v : v; }
__device__ __forceinline__ void load_lds16(const void* g, void* l) {
  __builtin_amdgcn_global_load_lds(
      (const __attribute__((address_space(1))) unsigned int*)g,
      (__attribute__((address_space(3))) unsigned int*)l, 16, 0, 0);
}

// ---------------------------------------------------------------- k_prep
// grid 80 x 256, 4 elems/thread: Wb = bf16(embW rows 0..63 || attnW rows 64..319)
__global__ __launch_bounds__(256) void k_prep(const float* __restrict__ embW,
                                              const float* __restrict__ attnW,
                                              unsigned short* __restrict__ Wb) {
  const int i = (blockIdx.x * 256 + threadIdx.x) * 4;   // 0..81916
  float4 v = (i < 16384) ? *(const float4*)(embW + i)
                         : *(const float4*)(attnW + (i - 16384));
  ushort4 p; p.x = f2bf(v.x); p.y = f2bf(v.y); p.z = f2bf(v.z); p.w = f2bf(v.w);
  *(ushort4*)(Wb + i) = p;
}

// ---------------------------------------------------------------- k_lin
// Fused emb+shortcut. grid 512 (64-row M-tiles), block 256 = 4 waves (2x2).
// Wave tile: 32 rows x 160 cols of the N=320 concatenated output.
// x staged from fp32 with inline pack2 (proven round-5 pattern); Wb pre-bf16.
__global__ __launch_bounds__(256) void k_lin(const float* __restrict__ x,
                                             const unsigned short* __restrict__ Wb,
                                             const float* __restrict__ embB,
                                             const float* __restrict__ attnB,
                                             const float* __restrict__ thrW,
                                             const float* __restrict__ thrB,
                                             unsigned short* __restrict__ embb,
                                             float* __restrict__ sq,
                                             unsigned short* __restrict__ scT,
                                             float* __restrict__ Tout) {
  __shared__ union {
    struct { unsigned short xs[64][40]; unsigned short ws[320][40]; } a;
    unsigned short St[256][72];
  } sm;
  const int t = threadIdx.x;
  const int Mbase = blockIdx.x * 64;
  const int lane = t & 63, wave = t >> 6;
  const int wm = wave >> 1, wn = wave & 1;
  const int l15 = lane & 15, quad = lane >> 4;

  f32x4 acc[2][10] = {};
  for (int k0 = 0; k0 < 256; k0 += 32) {
    { // stage x tile (64x32) from fp32, convert inline
      int row = t >> 2, c0 = (t & 3) * 8;
      const float* src = x + (size_t)(Mbase + row) * 256 + k0 + c0;
      float4 a = *(const float4*)src;
      float4 b = *(const float4*)(src + 4);
      uint4 p; p.x = pack2(a.x, a.y); p.y = pack2(a.z, a.w);
      p.z = pack2(b.x, b.y); p.w = pack2(b.z, b.w);
      *(uint4*)&sm.a.xs[row][c0] = p;
    }
    { // stage weight tile (320x32): pure copies from pre-converted Wb
      const unsigned short* wsrc = Wb + (size_t)t * 256 + k0;
      for (int s = 0; s < 4; s++)
        *(uint4*)&sm.a.ws[t][s * 8] = *(const uint4*)(wsrc + s * 8);
      if (t < 64) {
        const unsigned short* wsrc2 = Wb + (size_t)(256 + t) * 256 + k0;
        for (int s = 0; s < 4; s++)
          *(uint4*)&sm.a.ws[256 + t][s * 8] = *(const uint4*)(wsrc2 + s * 8);
      }
    }
    __syncthreads();
    bf16x8 af[2];
    af[0] = *(const bf16x8*)&sm.a.xs[wm * 32 + l15][quad * 8];
    af[1] = *(const bf16x8*)&sm.a.xs[wm * 32 + 16 + l15][quad * 8];
    for (int nt = 0; nt < 10; nt++) {
      bf16x8 bfr = *(const bf16x8*)&sm.a.ws[wn * 160 + nt * 16 + l15][quad * 8];
      acc[0][nt] = mfma16(af[0], bfr, acc[0][nt]);
      acc[1][nt] = mfma16(af[1], bfr, acc[1][nt]);
    }
    __syncthreads();
  }

  // emb epilogue: wn==0 waves own n<64 (nt 0..3); sq from ROUNDED emb.
  if (wn == 0) {
    float sp[2][4] = {{0.f,0.f,0.f,0.f},{0.f,0.f,0.f,0.f}};
    for (int rt = 0; rt < 2; rt++)
      for (int nt = 0; nt < 4; nt++) {
        int n = nt * 16 + l15;
        float bias = embB[n];
        for (int r = 0; r < 4; r++) {
          float v = acc[rt][nt][r] + bias;
          unsigned short hb = f2bf(v);
          int row = wm * 32 + rt * 16 + quad * 4 + r;
          embb[(size_t)(Mbase + row) * 64 + n] = hb;
          float vf = bf2f(hb);
          sp[rt][r] += vf * vf;
        }
      }
    for (int m = 8; m >= 1; m >>= 1)
      for (int rt = 0; rt < 2; rt++)
        for (int r = 0; r < 4; r++)
          sp[rt][r] += __shfl_xor(sp[rt][r], m);
    if (l15 == 0)
      for (int rt = 0; rt < 2; rt++)
        for (int r = 0; r < 4; r++)
          sq[Mbase + wm * 32 + rt * 16 + quad * 4 + r] = sp[rt][r];
  }

  // shortcut epilogue -> St transpose buffer
  for (int rt = 0; rt < 2; rt++)
    for (int nt = 0; nt < 10; nt++) {
      int n = wn * 160 + nt * 16 + l15;
      if (n < 64) continue;
      int c = n - 64;
      float bias = attnB[c];
      for (int r = 0; r < 4; r++) {
        float v = acc[rt][nt][r] + bias;
        sm.St[c][wm * 32 + rt * 16 + quad * 4 + r] = f2bf(v);
      }
    }
  __syncthreads();

  const int b = Mbase >> 10, jbase = Mbase & 1023;
  { // coalesced write of scT[b][c][jbase..jbase+64)
    unsigned short* dst = scT + ((size_t)b * 256 + t) * 1024 + jbase;
    for (int s = 0; s < 8; s++)
      *(uint4*)(dst + s * 8) = *(const uint4*)&sm.St[t][s * 8];
  }
  { // Tinst
    float tp = 0.f;
    int j = t >> 2, cs = (t & 3) * 64;
    for (int c = 0; c < 64; c++)
      tp += bf2f(sm.St[cs + c][j]) * thrW[cs + c];
    tp += __shfl_xor(tp, 1);
    tp += __shfl_xor(tp, 2);
    if ((t & 3) == 0) Tout[Mbase + j] = tp + thrB[0];
  }
}

// ---------------------------------------------------------------- k_scores
// grid 2048 (32 b x 64 strips of 16 rows), block 512 = 8 waves.
// Pass 1: wave w owns j-eighth [w*128,(w+1)*128); gram MFMA -> E in LDS + R.
// Pass 2: thread (row=t>>5, seg=t&31): u = exp(relu(E/R - T)) -> U, Z.
// 33.3KB LDS / 512 threads -> 4 blocks/CU = 32 waves/CU (2x round-7).
__global__ __launch_bounds__(512) void k_scores(const unsigned short* __restrict__ embb,
                                                const float* __restrict__ sq,
                                                const float* __restrict__ T,
                                                unsigned short* __restrict__ U,
                                                float* __restrict__ Z) {
  __shared__ unsigned short E_lds[16 * 1040];   // 33280 B
  __shared__ float rbuf[16];
  __shared__ float mtab[64];                    // exp(m(diff) - 1), diff 0..62
  const int t = threadIdx.x, lane = t & 63, wave = t >> 6;
  const int b = blockIdx.x >> 6, rb = (blockIdx.x & 63) * 16;
  const int l15 = lane & 15, quad = lane >> 4;
  const unsigned short* eb = embb + (size_t)b * 1024 * 64;

  if (t < 16) rbuf[t] = 0.f;
  if (t < 64) {
    float m = (t <= 32) ? (float)t * (1.f / 32.f) : 0.f;
    mtab[t] = __expf(m - 1.f);
  }
  __syncthreads();   // mtab + rbuf visible

  // ---- pass 1 (wave w: j in [w*128, w*128+128))
  const int rowA = rb + l15;
  bf16x8 a0 = *(const bf16x8*)(eb + (size_t)rowA * 64 + quad * 8);
  bf16x8 a1 = *(const bf16x8*)(eb + (size_t)rowA * 64 + 32 + quad * 8);
  const int rloc = quad * 4;
  // rows rloc..rloc+3 share y (4 | 32): hoist per-thread coords
  const int yi0 = (rb + rloc) >> 5, xi0 = (rb + rloc) & 31;
  float nsqi[4];
  for (int r = 0; r < 4; r++) nsqi[r] = -sq[b * 1024 + rb + rloc + r];
  const int jq = wave * 128;
  float rp[4] = {0.f, 0.f, 0.f, 0.f};
  for (int j0 = jq; j0 < jq + 128; j0 += 16) {
    const int jr = j0 + l15;
    bf16x8 b0 = *(const bf16x8*)(eb + (size_t)jr * 64 + quad * 8);
    bf16x8 b1 = *(const bf16x8*)(eb + (size_t)jr * 64 + 32 + quad * 8);
    f32x4 g = {0.f, 0.f, 0.f, 0.f};
    g = mfma16(a0, b0, g);
    g = mfma16(a1, b1, g);
    float sqj = sq[b * 1024 + jr];
    int dy = iabs(yi0 - (jr >> 5));
    int dxa = xi0 - (jr & 31);
    for (int r = 0; r < 4; r++) {
      float w = fminf(fmaf(2.f, g[r], nsqi[r] - sqj), 0.f);  // -d2, <= 0
      float v = __expf(w);                                    // exp(-d2)
      int diff = dy + iabs(dxa + r);
      float e = __expf(v) * mtab[diff];                       // exp(v - 1 + m)
      E_lds[(rloc + r) * 1040 + jr] = f2bf(e);
      rp[r] += e;   // unrounded sum: rel err ~1e-4 on R, damped in u
    }
  }
  for (int m = 8; m >= 1; m >>= 1)
    for (int r = 0; r < 4; r++)
      rp[r] += __shfl_xor(rp[r], m);
  __syncthreads();   // E_lds writes complete
  if (l15 == 0)
    for (int r = 0; r < 4; r++)
      atomicAdd(&rbuf[rloc + r], rp[r]);
  __syncthreads();   // R complete

  // ---- pass 2: row = t>>5 (0..15), seg = t&31 (0..31)
  const int prow = t >> 5, seg = t & 31;
  const float invR = 1.f / rbuf[prow];
  const float* Tb = T + b * 1024;
  unsigned short* ur = U + ((size_t)(b * 1024 + rb + prow)) * 1024;
  float z = 0.f;
  for (int c = 0; c < 4; c++) {
    int j = c * 256 + seg * 8;
    union { bf16x8 v; unsigned short s[8]; } ev;
    ev.v = *(const bf16x8*)&E_lds[prow * 1040 + j];
    float4 t0 = *(const float4*)(Tb + j);
    float4 t1 = *(const float4*)(Tb + j + 4);
    float tf[8] = {t0.x, t0.y, t0.z, t0.w, t1.x, t1.y, t1.z, t1.w};
    union { uint4 v; unsigned short s[8]; } uo;
    for (int k = 0; k < 8; k++) {
      float u = __expf(fmaxf(fmaf(bf2f(ev.s[k]), invR, -tf[k]), 0.f));
      unsigned short h = f2bf(u);
      uo.s[k] = h;
      z += bf2f(h);   // Z sums the ROUNDED u used by the GEMM
    }
    *(uint4*)(ur + j) = uo.v;
  }
  z += __shfl_xor(z, 1);
  z += __shfl_xor(z, 2);
  z += __shfl_xor(z, 4);
  z += __shfl_xor(z, 8);
  z += __shfl_xor(z, 16);
  if (seg == 0) Z[b * 1024 + rb + prow] = z;
}

// ---------------------------------------------------------------- k_out
// m97-style GEMM: out = x + (U @ scT^T) * invZ.  (unchanged)
__global__ __launch_bounds__(256) void k_out(const unsigned short* __restrict__ U,
                                             const float* __restrict__ Z,
                                             const unsigned short* __restrict__ scT,
                                             const float* __restrict__ x,
                                             float* __restrict__ out) {
  __shared__ unsigned short Ab[128 * 32];
  __shared__ unsigned short Bb[128 * 32];
  const int t = threadIdx.x, lane = t & 63, wave = t >> 6;
  const int wm = wave >> 1, wn = wave & 1;
  const int l15 = lane & 15, quad = lane >> 4;
  const int x8 = blockIdx.x & 7, s = blockIdx.x >> 3;
  const int b = x8 * 4 + (s >> 4), tile = s & 15;
  const int rb = (tile >> 1) * 128, cb = (tile & 1) * 128;

  const unsigned short* Ubase = U + (size_t)b * 1024 * 1024 + (size_t)rb * 1024;
  const unsigned short* Sbase = scT + (size_t)b * 256 * 1024 + (size_t)cb * 1024;

  int c0 = wave * 64 + lane;
  int c1 = c0 + 256;
  const int r0 = c0 >> 2, o0 = (c0 & 3) * 8;
  const int r1 = c1 >> 2, o1 = (c1 & 3) * 8;

  f32x4 acc[4][4] = {};
  for (int j0 = 0; j0 < 1024; j0 += 32) {
    load_lds16(Ubase + (size_t)r0 * 1024 + j0 + o0, Ab + c0 * 8);
    load_lds16(Ubase + (size_t)r1 * 1024 + j0 + o1, Ab + c1 * 8);
    load_lds16(Sbase + (size_t)r0 * 1024 + j0 + o0, Bb + c0 * 8);
    load_lds16(Sbase + (size_t)r1 * 1024 + j0 + o1, Bb + c1 * 8);
    __syncthreads();
    bf16x8 af[4], bf[4];
    for (int i = 0; i < 4; i++)
      af[i] = *(const bf16x8*)&Ab[(wm * 64 + i * 16 + l15) * 32 + quad * 8];
    for (int i = 0; i < 4; i++)
      bf[i] = *(const bf16x8*)&Bb[(wn * 64 + i * 16 + l15) * 32 + quad * 8];
    for (int i = 0; i < 4; i++)
      for (int j = 0; j < 4; j++)
        acc[i][j] = mfma16(af[i], bf[j], acc[i][j]);
    __syncthreads();
  }

  const int colb = cb + wn * 64;
  for (int i = 0; i < 4; i++) {
    int rowb = rb + wm * 64 + i * 16 + quad * 4;
    float iz[4];
    for (int r = 0; r < 4; r++) iz[r] = 1.f / Z[b * 1024 + rowb + r];
    for (int j = 0; j < 4; j++) {
      int c = colb + j * 16 + l15;
      for (int r = 0; r < 4; r++) {
        size_t idx = ((size_t)(b * 1024 + rowb + r)) * 256 + c;
        out[idx] = x[idx] + acc[i][j][r] * iz[r];
      }
    }
  }
}

// ---------------------------------------------------------------- launch
extern "C" void kernel_launch(void* const* d_in, const int* in_sizes, int n_in,
                              void* d_out, int out_size, void* d_ws, size_t ws_size,
                              hipStream_t stream) {
  const float* x     = (const float*)d_in[0];
  const float* embW  = (const float*)d_in[1];
  const float* embB  = (const float*)d_in[2];
  const float* attnW = (const float*)d_in[3];
  const float* attnB = (const float*)d_in[4];
  const float* thrW  = (const float*)d_in[5];
  const float* thrB  = (const float*)d_in[6];
  float* out = (float*)d_out;

  char* ws = (char*)d_ws;
  // layout: embb 4MB | scT 16MB | U 64MB | sq/T/Z tail
  // Wb (160KB) OVERLAPS U: dead before k_scores writes U.
  unsigned short* embb = (unsigned short*)(ws);
  unsigned short* scT  = (unsigned short*)(ws + (4ull << 20));
  unsigned short* U    = (unsigned short*)(ws + (20ull << 20));
  unsigned short* Wb   = (unsigned short*)(ws + (36ull << 20));   // overlap
  float* sq = (float*)(ws + (84ull << 20));
  float* T  = (float*)(ws + (84ull << 20) + (128ull << 10));
  float* Z  = (float*)(ws + (84ull << 20) + (256ull << 10));

  k_prep<<<80, 256, 0, stream>>>(embW, attnW, Wb);
  k_lin<<<512, 256, 0, stream>>>(x, Wb, embB, attnB, thrW, thrB, embb, sq, scT, T);
  k_scores<<<2048, 512, 0, stream>>>(embb, sq, T, U, Z);
  k_out<<<512, 256, 0, stream>>>(U, Z, scT, x, out);
}